// Round 7
// baseline (321.355 us; speedup 1.0000x reference)
//
#include <hip/hip_runtime.h>
#include <hip/hip_bf16.h>
#include <math.h>

#define NB 32768
#define ND 768
#define NC 474
#define NCP 512
#define NE 3
#define NH 128
#define GAP_THR 0.06f

typedef short v8s __attribute__((ext_vector_type(8)));
typedef float v4f __attribute__((ext_vector_type(4)));
typedef unsigned long long u64;

#define GLD16(gp, lp) __builtin_amdgcn_global_load_lds( \
    (const __attribute__((address_space(1))) void*)(gp), \
    (__attribute__((address_space(3))) void*)(lp), 16, 0, 0)

static __device__ __forceinline__ short f2bf(float f) {
    __hip_bfloat16 h = __float2bfloat16(f);
    return *reinterpret_cast<short*>(&h);
}

// ---------------------------------------------------------------------------
// prep: hwbT[e][c][k] = bf16(gamma[e][k]*hw[e][k][c]) transposed + slot-swizzled;
//       w1bT[c][k]    = bf16(w1[k][c]) same layout.
// Swizzle: within each 32-k (64B) group, 16B slot s -> s ^ ((c>>1)&3).
// ---------------------------------------------------------------------------
__global__ __launch_bounds__(256) void prep_kernel(
    const float* __restrict__ hw, const float* __restrict__ gamma,
    const float* __restrict__ w1,
    short* __restrict__ hwbT, short* __restrict__ w1bT)
{
    __shared__ float T[32][72];
    const int t = threadIdx.x;
    const int id = blockIdx.x;
    const float* src; short* dst; int stride, ncs; int e = 0, cc, kc;
    bool is_exp = (id < 576);
    if (is_exp) {
        e = id / 192; const int r2 = id % 192; cc = r2 / 24; kc = r2 % 24;
        src = hw + (size_t)e * ND * NC; stride = NC; ncs = NC;
        dst = hwbT + (size_t)e * NCP * ND;
    } else {
        const int j = id - 576; cc = j / 24; kc = j % 24;
        src = w1; stride = NH; ncs = NH; dst = w1bT;
    }
    const int c0 = cc * 64, k0 = kc * 32;
    {
        const int kl = t >> 3, c8 = (t & 7) * 8;
        const float g = is_exp ? gamma[e * ND + k0 + kl] : 1.f;
        #pragma unroll
        for (int j = 0; j < 8; ++j) {
            const int cg = c0 + c8 + j;
            const float v = (cg < ncs) ? src[(size_t)(k0 + kl) * stride + cg] : 0.f;
            T[kl][c8 + j] = v * g;
        }
    }
    __syncthreads();
    {
        const int cl = t >> 2, q = t & 3;
        const int cg = c0 + cl;
        const int sp = q ^ ((cg >> 1) & 3);
        union { short s[8]; int4 v; } u;
        #pragma unroll
        for (int j = 0; j < 8; ++j) u.s[j] = f2bf(T[q * 8 + j][cl]);
        *(int4*)(dst + (size_t)cg * ND + k0 + sp * 8) = u.v;
    }
}

// bias partials: bpart[e][kc][c] = sum_{k in chunk} beta[e][k]*hw[e][k][c]
__global__ __launch_bounds__(256) void bias_part_kernel(
    const float* __restrict__ hw, const float* __restrict__ beta,
    float* __restrict__ bpart)
{
    const int e = blockIdx.x, kc = blockIdx.y, t = threadIdx.x;
    const float* he = hw + (size_t)e * ND * NC;
    float a0 = 0.f, a1 = 0.f;
    const int c1 = t + 256;
    for (int k = kc * 48; k < kc * 48 + 48; ++k) {
        const float b = beta[e * ND + k];
        const float* row = he + (size_t)k * NC;
        a0 = fmaf(b, row[t], a0);
        if (c1 < NC) a1 = fmaf(b, row[c1], a1);
    }
    float* bp = bpart + (size_t)(e * 16 + kc) * NCP;
    bp[t] = a0;
    bp[c1] = (c1 < NC) ? a1 : 0.f;
}

__global__ __launch_bounds__(256) void bias_comb_kernel(
    const float* __restrict__ bpart, const float* __restrict__ hb,
    float* __restrict__ hbias)
{
    const int e = blockIdx.x, t = threadIdx.x;
    #pragma unroll
    for (int h = 0; h < 2; ++h) {
        const int c = t + h * 256;
        float s = 0.f;
        for (int kc = 0; kc < 16; ++kc)
            s += bpart[(size_t)(e * 16 + kc) * NCP + c];
        hbias[e * NCP + c] = (c < NC) ? hb[e * NC + c] + s : 0.f;
    }
}

// ---------------------------------------------------------------------------
// selector: 64 rows/block, burst A-stage + double-buffered B (GLD16).
// Epilogue: LN stats, logits, gap cascade; bucket append via ONE packed
// 64-bit atomic per block (4x16-bit fields), broadcast via __shfl (no LDS).
// ---------------------------------------------------------------------------
__global__ __launch_bounds__(256) void selector_kernel(
    const float* __restrict__ x, const float* __restrict__ gum,
    const short* __restrict__ w1bT, const float* __restrict__ b1,
    const float* __restrict__ w2, const float* __restrict__ b2,
    float2* __restrict__ murs, u64* __restrict__ counts,
    int* __restrict__ rowlist, int* __restrict__ redolist)
{
    __shared__ __align__(16) short As[64 * 392];   // 64 rows x 384k, stride 392
    __shared__ __align__(16) short Bs[2 * 4096];   // 2 x (128c x 32k)
    __shared__ float b1s[NH];
    __shared__ float w2s[NH * 3];
    __shared__ int besm[64];

    const int t = threadIdx.x;
    const int row0 = blockIdx.x * 64;
    const int w = t >> 6, l = t & 63;
    const int g = l >> 4, lm = l & 15;
    const int sr = t >> 2, sq = t & 3;

    if (t < NH) {
        b1s[t] = b1[t];
        w2s[t*3+0] = w2[t*3+0]; w2s[t*3+1] = w2[t*3+1]; w2s[t*3+2] = w2[t*3+2];
    }

    v4f acc[8];
    #pragma unroll
    for (int i = 0; i < 8; ++i) acc[i] = (v4f)(0.f);

    const float* xrow = x + (size_t)(row0 + sr) * ND + sq * 96;
    float s1 = 0.f, s2 = 0.f;
    int cur = 0;

    #pragma unroll 1
    for (int hf = 0; hf < 2; ++hf) {
        const int kh = hf * 384;
        float4 xv[24];
        #pragma unroll
        for (int i = 0; i < 24; ++i)
            xv[i] = *(const float4*)(xrow + kh + i * 4);
        #pragma unroll
        for (int i = 0; i < 2; ++i) {
            const int crow = w * 32 + i * 16 + (l >> 2);
            const int off = __builtin_amdgcn_readfirstlane(
                cur * 4096 + (w * 32 + i * 16) * 32);
            GLD16(w1bT + (size_t)crow * ND + kh + (l & 3) * 8, Bs + off);
        }
        __syncthreads();
        #pragma unroll
        for (int i = 0; i < 12; ++i) {
            const float4 a = xv[2*i], b = xv[2*i+1];
            s1 += a.x+a.y+a.z+a.w + b.x+b.y+b.z+b.w;
            s2 += a.x*a.x+a.y*a.y+a.z*a.z+a.w*a.w
                + b.x*b.x+b.y*b.y+b.z*b.z+b.w*b.w;
            v8s av;
            av[0]=f2bf(a.x); av[1]=f2bf(a.y); av[2]=f2bf(a.z); av[3]=f2bf(a.w);
            av[4]=f2bf(b.x); av[5]=f2bf(b.y); av[6]=f2bf(b.z); av[7]=f2bf(b.w);
            *(v8s*)&As[sr * 392 + sq * 96 + i * 8] = av;
        }
        __syncthreads();
        #pragma unroll 1
        for (int ks = 0; ks < 12; ++ks) {
            if (ks < 11) {
                #pragma unroll
                for (int i = 0; i < 2; ++i) {
                    const int crow = w * 32 + i * 16 + (l >> 2);
                    const int off = __builtin_amdgcn_readfirstlane(
                        (cur ^ 1) * 4096 + (w * 32 + i * 16) * 32);
                    GLD16(w1bT + (size_t)crow * ND + kh + (ks + 1) * 32 + (l & 3) * 8,
                          Bs + off);
                }
            }
            const v8s a = *(const v8s*)&As[(w * 16 + lm) * 392 + ks * 32 + g * 8];
            #pragma unroll
            for (int nf = 0; nf < 8; ++nf) {
                const int c = nf * 16 + lm;
                const v8s bv = *(const v8s*)&Bs[cur * 4096 + c * 32 + (g ^ ((c >> 1) & 3)) * 8];
                acc[nf] = __builtin_amdgcn_mfma_f32_16x16x32_bf16(a, bv, acc[nf], 0, 0, 0);
            }
            __syncthreads();
            cur ^= 1;
        }
    }

    // LN stats
    {
        float r1 = s1 + __shfl_xor(s1, 1);
        float r2 = s2 + __shfl_xor(s2, 1);
        r1 += __shfl_xor(r1, 2);
        r2 += __shfl_xor(r2, 2);
        if (sq == 0) {
            const float mu = r1 * (1.f/768.f);
            const float var = r2 * (1.f/768.f) - mu * mu;
            murs[row0 + sr] = make_float2(mu, rsqrtf(var + 1e-5f));
        }
    }

    // logits = relu(h + b1) @ w2, reduced across the 16 col-lanes
    float p[4][3];
    #pragma unroll
    for (int r = 0; r < 4; ++r) { p[r][0]=0.f; p[r][1]=0.f; p[r][2]=0.f; }
    #pragma unroll
    for (int nf = 0; nf < 8; ++nf) {
        const int c = nf * 16 + lm;
        const float bb = b1s[c];
        const float wa = w2s[c*3], wb = w2s[c*3+1], wcc = w2s[c*3+2];
        #pragma unroll
        for (int r = 0; r < 4; ++r) {
            const float h = fmaxf(acc[nf][r] + bb, 0.f);
            p[r][0] = fmaf(h, wa,  p[r][0]);
            p[r][1] = fmaf(h, wb,  p[r][1]);
            p[r][2] = fmaf(h, wcc, p[r][2]);
        }
    }
    #pragma unroll
    for (int m = 1; m < 16; m <<= 1) {
        #pragma unroll
        for (int r = 0; r < 4; ++r) {
            p[r][0] += __shfl_xor(p[r][0], m);
            p[r][1] += __shfl_xor(p[r][1], m);
            p[r][2] += __shfl_xor(p[r][2], m);
        }
    }
    if (lm == 0) {
        const float bb0 = b2[0], bb1 = b2[1], bb2 = b2[2];
        #pragma unroll
        for (int r = 0; r < 4; ++r) {
            const int rl = w * 16 + g * 4 + r;
            const int grow = row0 + rl;
            const float z0 = p[r][0] + bb0 + gum[grow*3+0];
            const float z1 = p[r][1] + bb1 + gum[grow*3+1];
            const float z2 = p[r][2] + bb2 + gum[grow*3+2];
            int be = 0; float best = z0;
            if (z1 > best) { best = z1; be = 1; }
            if (z2 > best) { best = z2; be = 2; }
            const float second = (be==0) ? fmaxf(z1,z2) : (be==1) ? fmaxf(z0,z2) : fmaxf(z0,z1);
            besm[rl] = (best - second < GAP_THR) ? 3 : be;
        }
    }
    __syncthreads();

    // wave 0: ballot-aggregate 64 decisions -> ONE packed atomic; shfl broadcast
    if (w == 0) {
        const int be = besm[l];
        const u64 m0 = __ballot(be == 0);
        const u64 m1 = __ballot(be == 1);
        const u64 m2 = __ballot(be == 2);
        const u64 m3 = __ballot(be == 3);
        u64 old = 0;
        if (l == 0) {
            const u64 add = (u64)__popcll(m0)
                          | ((u64)__popcll(m1) << 16)
                          | ((u64)__popcll(m2) << 32)
                          | ((u64)__popcll(m3) << 48);
            old = atomicAdd(counts, add);
        }
        // broadcast 64-bit old value from lane 0 via two 32-bit shuffles
        const int blo = __shfl((int)(old & 0xFFFFFFFFull), 0);
        const int bhi = __shfl((int)(old >> 32), 0);
        old = ((u64)(unsigned)bhi << 32) | (u64)(unsigned)blo;
        const u64 mym = (be == 0) ? m0 : (be == 1) ? m1 : (be == 2) ? m2 : m3;
        const u64 below = (l == 63) ? 0x7FFFFFFFFFFFFFFFull : ((1ull << l) - 1ull);
        const int rank = __popcll(mym & below);
        const int base = (int)((old >> (16 * be)) & 0xFFFFull);
        const int idx = base + rank;
        const int grow = row0 + l;
        if (be < 3) {
            if ((unsigned)idx < NB) rowlist[be * NB + idx] = grow;
        } else {
            if ((unsigned)idx < NB) redolist[idx] = grow;
        }
    }
}

// fp64 redo for ambiguous rows
__global__ __launch_bounds__(128) void redo_kernel(
    const float* __restrict__ x, const float* __restrict__ gum,
    const float* __restrict__ w1, const float* __restrict__ b1,
    const float* __restrict__ w2, const float* __restrict__ b2,
    u64* __restrict__ counts, int* __restrict__ rowlist,
    const int* __restrict__ redolist)
{
    const int t = threadIdx.x;
    int n = (int)((*counts >> 48) & 0xFFFFull);
    if (n > NB) n = NB;
    __shared__ double red[2][3];
    for (int i = blockIdx.x; i < n; i += gridDim.x) {
        const int row = redolist[i];
        const float* xr = x + (size_t)row * ND;
        double h = 0.0;
        for (int k = 0; k < ND; ++k)
            h = fma((double)xr[k], (double)w1[(size_t)k * NH + t], h);
        h += (double)b1[t];
        h = h > 0.0 ? h : 0.0;
        double p0 = h * (double)w2[t * 3 + 0];
        double p1 = h * (double)w2[t * 3 + 1];
        double p2 = h * (double)w2[t * 3 + 2];
        #pragma unroll
        for (int m = 32; m >= 1; m >>= 1) {
            p0 += __shfl_xor(p0, m);
            p1 += __shfl_xor(p1, m);
            p2 += __shfl_xor(p2, m);
        }
        if ((t & 63) == 0) {
            red[t >> 6][0] = p0; red[t >> 6][1] = p1; red[t >> 6][2] = p2;
        }
        __syncthreads();
        if (t == 0) {
            double best = 0.0; int be = 0;
            #pragma unroll
            for (int e = 0; e < NE; ++e) {
                const double z = red[0][e] + red[1][e] + (double)b2[e]
                               + (double)gum[(size_t)row * 3 + e];
                if (e == 0 || z > best) { best = z; be = e; }
            }
            const u64 old = atomicAdd(counts, 1ull << (16 * be));
            const int pos = (int)((old >> (16 * be)) & 0xFFFFull);
            if ((unsigned)pos < NB) rowlist[be * NB + pos] = row;
        }
        __syncthreads();
    }
}

// ---------------------------------------------------------------------------
// head: grouped bf16 MFMA GEMM, BM=64 x BN=512(padded NC).
// x held in registers (192 floats/thread -> 24 v8s bf16); A staged per-32k
// double-buffered from regs; B double-buffered via GLD16. LDS 78 KB ->
// 2 blocks/CU for wave-level stall overlap. K-loop fully unrolled.
// ---------------------------------------------------------------------------
__global__ __launch_bounds__(256, 2) void head_kernel(
    const float* __restrict__ x, const float2* __restrict__ murs,
    const short* __restrict__ hwbT, const float* __restrict__ hbias,
    const u64* __restrict__ counts, const int* __restrict__ rowlist,
    float* __restrict__ out)
{
    const int e = blockIdx.z;
    int cnt = (int)((*counts >> (16 * e)) & 0xFFFFull);
    if (cnt > NB) cnt = NB;
    const int rc0 = blockIdx.y * 64;
    if (rc0 >= cnt) return;

    __shared__ __align__(16) short As[2][64 * 40];  // dbuf 32-k A slabs, stride 40
    __shared__ __align__(16) short Bs[2 * 16384];   // dbuf 512c x 32k
    __shared__ float hbs[NCP];
    __shared__ int rows_s[64];

    const int t = threadIdx.x;
    const int w = t >> 6, l = t & 63;
    const int g = l >> 4, lm = l & 15;
    const int sr = t >> 2, sq = t & 3;

    const int ridx = rc0 + sr;
    const bool av = ridx < cnt;
    int arow = av ? rowlist[e * NB + ridx] : 0;
    if ((unsigned)arow >= NB) arow = 0;
    float mu = 0.f, rs = 0.f;
    if (av) { const float2 mr = murs[arow]; mu = mr.x; rs = mr.y; }
    const float nm = -mu * rs;
    const float* xrow = x + (size_t)arow * ND + sq * 192;

    if (t < 64) {
        const int ri = rc0 + t;
        int rr = (ri < cnt) ? rowlist[e * NB + ri] : -1;
        if (rr >= NB) rr = -1;
        rows_s[t] = rr;
    }
    hbs[t] = hbias[e * NCP + t];
    hbs[t + 256] = hbias[e * NCP + t + 256];
    const short* hwe = hwbT + (size_t)e * NCP * ND;

    // burst-load this thread's 192 x-floats, normalize, convert to bf16 regs
    v8s xr[24];
    #pragma unroll
    for (int i = 0; i < 24; ++i) {
        float4 a = make_float4(0.f, 0.f, 0.f, 0.f), b = a;
        if (av) {
            a = *(const float4*)(xrow + i * 8);
            b = *(const float4*)(xrow + i * 8 + 4);
        }
        v8s v;
        v[0]=f2bf(fmaf(a.x,rs,nm)); v[1]=f2bf(fmaf(a.y,rs,nm));
        v[2]=f2bf(fmaf(a.z,rs,nm)); v[3]=f2bf(fmaf(a.w,rs,nm));
        v[4]=f2bf(fmaf(b.x,rs,nm)); v[5]=f2bf(fmaf(b.y,rs,nm));
        v[6]=f2bf(fmaf(b.z,rs,nm)); v[7]=f2bf(fmaf(b.w,rs,nm));
        xr[i] = v;
    }

    v4f acc[4][8];
    #pragma unroll
    for (int i = 0; i < 4; ++i)
        #pragma unroll
        for (int j = 0; j < 8; ++j) acc[i][j] = (v4f)(0.f);

    // prologue: stage ks=0 (A owner: sq==0; B tile 0)
    if (sq == 0) {
        #pragma unroll
        for (int j = 0; j < 4; ++j)
            *(v8s*)&As[0][sr * 40 + j * 8] = xr[j];
    }
    #pragma unroll
    for (int i = 0; i < 8; ++i) {
        const int crow = w * 128 + i * 16 + (l >> 2);
        const int off = __builtin_amdgcn_readfirstlane((w * 128 + i * 16) * 32);
        GLD16(hwe + (size_t)crow * ND + (l & 3) * 8, Bs + off);
    }
    __syncthreads();

    #pragma unroll
    for (int ks = 0; ks < 24; ++ks) {
        const int cur = ks & 1;
        const int nxt = cur ^ 1;
        if (ks < 23) {
            const int kn = ks + 1;
            // A slab for window kn, from owner quarter's registers
            if (sq == kn / 6) {
                const int i0 = (kn % 6) * 4;
                #pragma unroll
                for (int j = 0; j < 4; ++j)
                    *(v8s*)&As[nxt][sr * 40 + j * 8] = xr[i0 + j];
            }
            // B tile for window kn
            #pragma unroll
            for (int i = 0; i < 8; ++i) {
                const int crow = w * 128 + i * 16 + (l >> 2);
                const int off = __builtin_amdgcn_readfirstlane(
                    nxt * 16384 + (w * 128 + i * 16) * 32);
                GLD16(hwe + (size_t)crow * ND + kn * 32 + (l & 3) * 8, Bs + off);
            }
        }
        v8s af[4];
        #pragma unroll
        for (int mf = 0; mf < 4; ++mf)
            af[mf] = *(const v8s*)&As[cur][(mf * 16 + lm) * 40 + g * 8];
        #pragma unroll
        for (int nf = 0; nf < 8; ++nf) {
            const int c = w * 128 + nf * 16 + lm;
            const v8s bv = *(const v8s*)&Bs[cur * 16384 + c * 32 + (g ^ ((c >> 1) & 3)) * 8];
            #pragma unroll
            for (int mf = 0; mf < 4; ++mf)
                acc[mf][nf] = __builtin_amdgcn_mfma_f32_16x16x32_bf16(
                    af[mf], bv, acc[mf][nf], 0, 0, 0);
        }
        __syncthreads();
    }

    #pragma unroll
    for (int mf = 0; mf < 4; ++mf) {
        #pragma unroll
        for (int r = 0; r < 4; ++r) {
            const int rl = mf * 16 + g * 4 + r;
            const int orow = rows_s[rl];
            if (orow < 0) continue;
            float* op = out + (size_t)orow * NC;
            #pragma unroll
            for (int nf = 0; nf < 8; ++nf) {
                const int c = w * 128 + nf * 16 + lm;
                if (c < NC) op[c] = acc[mf][nf][r] + hbs[c];
            }
        }
    }
}

extern "C" void kernel_launch(void* const* d_in, const int* in_sizes, int n_in,
                              void* d_out, int out_size, void* d_ws, size_t ws_size,
                              hipStream_t stream) {
    const float* x     = (const float*)d_in[0];
    const float* gum   = (const float*)d_in[1];
    const float* w1    = (const float*)d_in[2];
    const float* b1    = (const float*)d_in[3];
    const float* w2    = (const float*)d_in[4];
    const float* b2    = (const float*)d_in[5];
    const float* gamma = (const float*)d_in[6];
    const float* beta  = (const float*)d_in[7];
    const float* hw    = (const float*)d_in[8];
    const float* hb    = (const float*)d_in[9];
    float* out = (float*)d_out;

    char* ws = (char*)d_ws;
    u64*    counts   = (u64*)ws;                    // packed 4x16-bit counters
    float2* murs     = (float2*)(ws + 256);         // 262144 B
    int*    rowlist  = (int*)(ws + 262400);         // 393216 B
    int*    redolist = (int*)(ws + 655616);         // 131072 B
    float*  hbias    = (float*)(ws + 786688);       // 6144 B
    float*  bpart    = (float*)(ws + 792832);       // 98304 B
    short*  w1bT     = (short*)(ws + 891136);       // 196608 B
    short*  hwbT     = (short*)(ws + 1087744);      // 2359296 B

    hipMemsetAsync(counts, 0, 16, stream);
    prep_kernel<<<624, 256, 0, stream>>>(hw, gamma, w1, hwbT, w1bT);
    bias_part_kernel<<<dim3(3, 16), 256, 0, stream>>>(hw, beta, bpart);
    bias_comb_kernel<<<3, 256, 0, stream>>>(bpart, hb, hbias);
    selector_kernel<<<NB / 64, 256, 0, stream>>>(x, gum, w1bT, b1, w2, b2,
                                                 murs, counts, rowlist, redolist);
    redo_kernel<<<512, 128, 0, stream>>>(x, gum, w1, b1, w2, b2,
                                         counts, rowlist, redolist);
    head_kernel<<<dim3(1, NB / 64, NE), 256, 0, stream>>>(
        x, murs, hwbT, hbias, counts, rowlist, out);
}

// Round 8
// 249.316 us; speedup vs baseline: 1.2889x; 1.2889x over previous
//
#include <hip/hip_runtime.h>
#include <hip/hip_bf16.h>
#include <math.h>

#define NB 32768
#define ND 768
#define NC 474
#define NCP 512
#define NE 3
#define NH 128
#define GAP_THR 0.06f

typedef short v8s __attribute__((ext_vector_type(8)));
typedef float v4f __attribute__((ext_vector_type(4)));
typedef unsigned long long u64;

#define GLD16(gp, lp) __builtin_amdgcn_global_load_lds( \
    (const __attribute__((address_space(1))) void*)(gp), \
    (__attribute__((address_space(3))) void*)(lp), 16, 0, 0)

static __device__ __forceinline__ short f2bf(float f) {
    __hip_bfloat16 h = __float2bfloat16(f);
    return *reinterpret_cast<short*>(&h);
}

// ---------------------------------------------------------------------------
// prep: hwbT[e][c][k] = bf16(gamma[e][k]*hw[e][k][c]) transposed + slot-swizzled;
//       w1bT[c][k]    = bf16(w1[k][c]) same layout.
// Swizzle: within each 32-k (64B) group, 16B slot s -> s ^ ((c>>1)&3).
// ---------------------------------------------------------------------------
__global__ __launch_bounds__(256) void prep_kernel(
    const float* __restrict__ hw, const float* __restrict__ gamma,
    const float* __restrict__ w1,
    short* __restrict__ hwbT, short* __restrict__ w1bT)
{
    __shared__ float T[32][72];
    const int t = threadIdx.x;
    const int id = blockIdx.x;
    const float* src; short* dst; int stride, ncs; int e = 0, cc, kc;
    bool is_exp = (id < 576);
    if (is_exp) {
        e = id / 192; const int r2 = id % 192; cc = r2 / 24; kc = r2 % 24;
        src = hw + (size_t)e * ND * NC; stride = NC; ncs = NC;
        dst = hwbT + (size_t)e * NCP * ND;
    } else {
        const int j = id - 576; cc = j / 24; kc = j % 24;
        src = w1; stride = NH; ncs = NH; dst = w1bT;
    }
    const int c0 = cc * 64, k0 = kc * 32;
    {
        const int kl = t >> 3, c8 = (t & 7) * 8;
        const float g = is_exp ? gamma[e * ND + k0 + kl] : 1.f;
        #pragma unroll
        for (int j = 0; j < 8; ++j) {
            const int cg = c0 + c8 + j;
            const float v = (cg < ncs) ? src[(size_t)(k0 + kl) * stride + cg] : 0.f;
            T[kl][c8 + j] = v * g;
        }
    }
    __syncthreads();
    {
        const int cl = t >> 2, q = t & 3;
        const int cg = c0 + cl;
        const int sp = q ^ ((cg >> 1) & 3);
        union { short s[8]; int4 v; } u;
        #pragma unroll
        for (int j = 0; j < 8; ++j) u.s[j] = f2bf(T[q * 8 + j][cl]);
        *(int4*)(dst + (size_t)cg * ND + k0 + sp * 8) = u.v;
    }
}

// partials over 48-k chunks: bpB = beta@hw, bpG = gamma@hw
__global__ __launch_bounds__(256) void bias_part_kernel(
    const float* __restrict__ hw, const float* __restrict__ beta,
    const float* __restrict__ gamma,
    float* __restrict__ bpB, float* __restrict__ bpG)
{
    const int e = blockIdx.x, kc = blockIdx.y, t = threadIdx.x;
    const float* he = hw + (size_t)e * ND * NC;
    float a0 = 0.f, a1 = 0.f, g0 = 0.f, g1 = 0.f;
    const int c1 = t + 256;
    for (int k = kc * 48; k < kc * 48 + 48; ++k) {
        const float b = beta[e * ND + k];
        const float gm = gamma[e * ND + k];
        const float* row = he + (size_t)k * NC;
        const float v0 = row[t];
        a0 = fmaf(b, v0, a0);
        g0 = fmaf(gm, v0, g0);
        if (c1 < NC) {
            const float v1 = row[c1];
            a1 = fmaf(b, v1, a1);
            g1 = fmaf(gm, v1, g1);
        }
    }
    const size_t o = (size_t)(e * 16 + kc) * NCP;
    bpB[o + t] = a0;
    bpB[o + c1] = (c1 < NC) ? a1 : 0.f;
    bpG[o + t] = g0;
    bpG[o + c1] = (c1 < NC) ? g1 : 0.f;
}

__global__ __launch_bounds__(256) void bias_comb_kernel(
    const float* __restrict__ bpB, const float* __restrict__ bpG,
    const float* __restrict__ hb,
    float* __restrict__ hbias, float* __restrict__ csumv)
{
    const int e = blockIdx.x, t = threadIdx.x;
    #pragma unroll
    for (int h = 0; h < 2; ++h) {
        const int c = t + h * 256;
        float sb = 0.f, sg = 0.f;
        for (int kc = 0; kc < 16; ++kc) {
            sb += bpB[(size_t)(e * 16 + kc) * NCP + c];
            sg += bpG[(size_t)(e * 16 + kc) * NCP + c];
        }
        hbias[e * NCP + c] = (c < NC) ? hb[e * NC + c] + sb : 0.f;
        csumv[e * NCP + c] = (c < NC) ? sg : 0.f;
    }
}

// ---------------------------------------------------------------------------
// selector: 64 rows/block, burst A-stage + double-buffered B (GLD16).
// Epilogue: LN stats, logits, gap cascade; bucket append via ONE packed
// 64-bit atomic per block (4x16-bit fields), broadcast via __shfl (no LDS).
// ---------------------------------------------------------------------------
__global__ __launch_bounds__(256) void selector_kernel(
    const float* __restrict__ x, const float* __restrict__ gum,
    const short* __restrict__ w1bT, const float* __restrict__ b1,
    const float* __restrict__ w2, const float* __restrict__ b2,
    float2* __restrict__ murs, u64* __restrict__ counts,
    int* __restrict__ rowlist, int* __restrict__ redolist)
{
    __shared__ __align__(16) short As[64 * 392];   // 64 rows x 384k, stride 392
    __shared__ __align__(16) short Bs[2 * 4096];   // 2 x (128c x 32k)
    __shared__ float b1s[NH];
    __shared__ float w2s[NH * 3];
    __shared__ int besm[64];

    const int t = threadIdx.x;
    const int row0 = blockIdx.x * 64;
    const int w = t >> 6, l = t & 63;
    const int g = l >> 4, lm = l & 15;
    const int sr = t >> 2, sq = t & 3;

    if (t < NH) {
        b1s[t] = b1[t];
        w2s[t*3+0] = w2[t*3+0]; w2s[t*3+1] = w2[t*3+1]; w2s[t*3+2] = w2[t*3+2];
    }

    v4f acc[8];
    #pragma unroll
    for (int i = 0; i < 8; ++i) acc[i] = (v4f)(0.f);

    const float* xrow = x + (size_t)(row0 + sr) * ND + sq * 96;
    float s1 = 0.f, s2 = 0.f;
    int cur = 0;

    #pragma unroll 1
    for (int hf = 0; hf < 2; ++hf) {
        const int kh = hf * 384;
        float4 xv[24];
        #pragma unroll
        for (int i = 0; i < 24; ++i)
            xv[i] = *(const float4*)(xrow + kh + i * 4);
        #pragma unroll
        for (int i = 0; i < 2; ++i) {
            const int crow = w * 32 + i * 16 + (l >> 2);
            const int off = __builtin_amdgcn_readfirstlane(
                cur * 4096 + (w * 32 + i * 16) * 32);
            GLD16(w1bT + (size_t)crow * ND + kh + (l & 3) * 8, Bs + off);
        }
        __syncthreads();
        #pragma unroll
        for (int i = 0; i < 12; ++i) {
            const float4 a = xv[2*i], b = xv[2*i+1];
            s1 += a.x+a.y+a.z+a.w + b.x+b.y+b.z+b.w;
            s2 += a.x*a.x+a.y*a.y+a.z*a.z+a.w*a.w
                + b.x*b.x+b.y*b.y+b.z*b.z+b.w*b.w;
            v8s av;
            av[0]=f2bf(a.x); av[1]=f2bf(a.y); av[2]=f2bf(a.z); av[3]=f2bf(a.w);
            av[4]=f2bf(b.x); av[5]=f2bf(b.y); av[6]=f2bf(b.z); av[7]=f2bf(b.w);
            *(v8s*)&As[sr * 392 + sq * 96 + i * 8] = av;
        }
        __syncthreads();
        #pragma unroll 1
        for (int ks = 0; ks < 12; ++ks) {
            if (ks < 11) {
                #pragma unroll
                for (int i = 0; i < 2; ++i) {
                    const int crow = w * 32 + i * 16 + (l >> 2);
                    const int off = __builtin_amdgcn_readfirstlane(
                        (cur ^ 1) * 4096 + (w * 32 + i * 16) * 32);
                    GLD16(w1bT + (size_t)crow * ND + kh + (ks + 1) * 32 + (l & 3) * 8,
                          Bs + off);
                }
            }
            const v8s a = *(const v8s*)&As[(w * 16 + lm) * 392 + ks * 32 + g * 8];
            #pragma unroll
            for (int nf = 0; nf < 8; ++nf) {
                const int c = nf * 16 + lm;
                const v8s bv = *(const v8s*)&Bs[cur * 4096 + c * 32 + (g ^ ((c >> 1) & 3)) * 8];
                acc[nf] = __builtin_amdgcn_mfma_f32_16x16x32_bf16(a, bv, acc[nf], 0, 0, 0);
            }
            __syncthreads();
            cur ^= 1;
        }
    }

    // LN stats
    {
        float r1 = s1 + __shfl_xor(s1, 1);
        float r2 = s2 + __shfl_xor(s2, 1);
        r1 += __shfl_xor(r1, 2);
        r2 += __shfl_xor(r2, 2);
        if (sq == 0) {
            const float mu = r1 * (1.f/768.f);
            const float var = r2 * (1.f/768.f) - mu * mu;
            murs[row0 + sr] = make_float2(mu, rsqrtf(var + 1e-5f));
        }
    }

    // logits = relu(h + b1) @ w2, reduced across the 16 col-lanes
    float p[4][3];
    #pragma unroll
    for (int r = 0; r < 4; ++r) { p[r][0]=0.f; p[r][1]=0.f; p[r][2]=0.f; }
    #pragma unroll
    for (int nf = 0; nf < 8; ++nf) {
        const int c = nf * 16 + lm;
        const float bb = b1s[c];
        const float wa = w2s[c*3], wb = w2s[c*3+1], wcc = w2s[c*3+2];
        #pragma unroll
        for (int r = 0; r < 4; ++r) {
            const float h = fmaxf(acc[nf][r] + bb, 0.f);
            p[r][0] = fmaf(h, wa,  p[r][0]);
            p[r][1] = fmaf(h, wb,  p[r][1]);
            p[r][2] = fmaf(h, wcc, p[r][2]);
        }
    }
    #pragma unroll
    for (int m = 1; m < 16; m <<= 1) {
        #pragma unroll
        for (int r = 0; r < 4; ++r) {
            p[r][0] += __shfl_xor(p[r][0], m);
            p[r][1] += __shfl_xor(p[r][1], m);
            p[r][2] += __shfl_xor(p[r][2], m);
        }
    }
    if (lm == 0) {
        const float bb0 = b2[0], bb1 = b2[1], bb2 = b2[2];
        #pragma unroll
        for (int r = 0; r < 4; ++r) {
            const int rl = w * 16 + g * 4 + r;
            const int grow = row0 + rl;
            const float z0 = p[r][0] + bb0 + gum[grow*3+0];
            const float z1 = p[r][1] + bb1 + gum[grow*3+1];
            const float z2 = p[r][2] + bb2 + gum[grow*3+2];
            int be = 0; float best = z0;
            if (z1 > best) { best = z1; be = 1; }
            if (z2 > best) { best = z2; be = 2; }
            const float second = (be==0) ? fmaxf(z1,z2) : (be==1) ? fmaxf(z0,z2) : fmaxf(z0,z1);
            besm[rl] = (best - second < GAP_THR) ? 3 : be;
        }
    }
    __syncthreads();

    // wave 0: ballot-aggregate 64 decisions -> ONE packed atomic; shfl broadcast
    if (w == 0) {
        const int be = besm[l];
        const u64 m0 = __ballot(be == 0);
        const u64 m1 = __ballot(be == 1);
        const u64 m2 = __ballot(be == 2);
        const u64 m3 = __ballot(be == 3);
        u64 old = 0;
        if (l == 0) {
            const u64 add = (u64)__popcll(m0)
                          | ((u64)__popcll(m1) << 16)
                          | ((u64)__popcll(m2) << 32)
                          | ((u64)__popcll(m3) << 48);
            old = atomicAdd(counts, add);
        }
        const int blo = __shfl((int)(old & 0xFFFFFFFFull), 0);
        const int bhi = __shfl((int)(old >> 32), 0);
        old = ((u64)(unsigned)bhi << 32) | (u64)(unsigned)blo;
        const u64 mym = (be == 0) ? m0 : (be == 1) ? m1 : (be == 2) ? m2 : m3;
        const u64 below = (l == 63) ? 0x7FFFFFFFFFFFFFFFull : ((1ull << l) - 1ull);
        const int rank = __popcll(mym & below);
        const int base = (int)((old >> (16 * be)) & 0xFFFFull);
        const int idx = base + rank;
        const int grow = row0 + l;
        if (be < 3) {
            if ((unsigned)idx < NB) rowlist[be * NB + idx] = grow;
        } else {
            if ((unsigned)idx < NB) redolist[idx] = grow;
        }
    }
}

// fp64 redo for ambiguous rows
__global__ __launch_bounds__(128) void redo_kernel(
    const float* __restrict__ x, const float* __restrict__ gum,
    const float* __restrict__ w1, const float* __restrict__ b1,
    const float* __restrict__ w2, const float* __restrict__ b2,
    u64* __restrict__ counts, int* __restrict__ rowlist,
    const int* __restrict__ redolist)
{
    const int t = threadIdx.x;
    int n = (int)((*counts >> 48) & 0xFFFFull);
    if (n > NB) n = NB;
    __shared__ double red[2][3];
    for (int i = blockIdx.x; i < n; i += gridDim.x) {
        const int row = redolist[i];
        const float* xr = x + (size_t)row * ND;
        double h = 0.0;
        for (int k = 0; k < ND; ++k)
            h = fma((double)xr[k], (double)w1[(size_t)k * NH + t], h);
        h += (double)b1[t];
        h = h > 0.0 ? h : 0.0;
        double p0 = h * (double)w2[t * 3 + 0];
        double p1 = h * (double)w2[t * 3 + 1];
        double p2 = h * (double)w2[t * 3 + 2];
        #pragma unroll
        for (int m = 32; m >= 1; m >>= 1) {
            p0 += __shfl_xor(p0, m);
            p1 += __shfl_xor(p1, m);
            p2 += __shfl_xor(p2, m);
        }
        if ((t & 63) == 0) {
            red[t >> 6][0] = p0; red[t >> 6][1] = p1; red[t >> 6][2] = p2;
        }
        __syncthreads();
        if (t == 0) {
            double best = 0.0; int be = 0;
            #pragma unroll
            for (int e = 0; e < NE; ++e) {
                const double z = red[0][e] + red[1][e] + (double)b2[e]
                               + (double)gum[(size_t)row * 3 + e];
                if (e == 0 || z > best) { best = z; be = e; }
            }
            const u64 old = atomicAdd(counts, 1ull << (16 * be));
            const int pos = (int)((old >> (16 * be)) & 0xFFFFull);
            if ((unsigned)pos < NB) rowlist[be * NB + pos] = row;
        }
        __syncthreads();
    }
}

// ---------------------------------------------------------------------------
// head: grouped bf16 MFMA GEMM on RAW x (normalization folded into epilogue:
// out = rs*(x@Wg) - rs*mu*csum + hbias). BM=64 x BN=256, BK=32 double-buffered.
// A slab 4 KB from 32B/thread reg loads; B via GLD16. LDS ~43 KB -> 3 blk/CU.
// ---------------------------------------------------------------------------
__global__ __launch_bounds__(256, 3) void head_kernel(
    const float* __restrict__ x, const float2* __restrict__ murs,
    const short* __restrict__ hwbT, const float* __restrict__ hbias,
    const float* __restrict__ csumv,
    const u64* __restrict__ counts, const int* __restrict__ rowlist,
    float* __restrict__ out)
{
    const int e = blockIdx.z;
    int cnt = (int)((*counts >> (16 * e)) & 0xFFFFull);
    if (cnt > NB) cnt = NB;
    const int rc0 = blockIdx.y * 64;
    if (rc0 >= cnt) return;
    const int n0 = blockIdx.x * 256;

    __shared__ __align__(16) short As[2][64 * 32];   // dbuf 64 rows x 32k
    __shared__ __align__(16) short Bs[2][256 * 32];  // dbuf 256c x 32k
    __shared__ float hbs[256], css[256], rs_s[64], rm_s[64];
    __shared__ int rows_s[64];

    const int t = threadIdx.x;
    const int w = t >> 6, l = t & 63;
    const int g = l >> 4, lm = l & 15;
    const int sr = t >> 2, sq = t & 3;

    if (t < 64) {
        const int ri = rc0 + t;
        int rr = (ri < cnt) ? rowlist[e * NB + ri] : -1;
        if (rr >= NB) rr = -1;
        rows_s[t] = rr;
        const float2 mr = (rr >= 0) ? murs[rr] : make_float2(0.f, 0.f);
        rs_s[t] = mr.y;
        rm_s[t] = mr.y * mr.x;   // rs*mu
    }
    hbs[t] = (n0 + t < NC) ? hbias[e * NCP + n0 + t] : 0.f;
    css[t] = (n0 + t < NC) ? csumv[e * NCP + n0 + t] : 0.f;

    // this thread's A-source row (raw x, fp32)
    const int ridx = rc0 + sr;
    int arow = (ridx < cnt) ? rowlist[e * NB + ridx] : 0;
    if ((unsigned)arow >= NB) arow = 0;
    const float* xsrc = x + (size_t)arow * ND + sq * 8;
    const int aslot = sq ^ ((sr >> 1) & 3);       // write-side swizzle
    const short* hwe = hwbT + (size_t)e * NCP * ND + (size_t)n0 * ND;

    v4f acc[4][4];
    #pragma unroll
    for (int i = 0; i < 4; ++i)
        #pragma unroll
        for (int j = 0; j < 4; ++j) acc[i][j] = (v4f)(0.f);

    // prologue: stage ks=0
    {
        const float4 a = *(const float4*)(xsrc);
        const float4 b = *(const float4*)(xsrc + 4);
        v8s v;
        v[0]=f2bf(a.x); v[1]=f2bf(a.y); v[2]=f2bf(a.z); v[3]=f2bf(a.w);
        v[4]=f2bf(b.x); v[5]=f2bf(b.y); v[6]=f2bf(b.z); v[7]=f2bf(b.w);
        *(v8s*)&As[0][sr * 32 + aslot * 8] = v;
        #pragma unroll
        for (int i = 0; i < 4; ++i) {
            const int crow = w * 64 + i * 16 + (l >> 2);
            const int off = __builtin_amdgcn_readfirstlane((w * 64 + i * 16) * 32);
            GLD16(hwe + (size_t)crow * ND + (l & 3) * 8, &Bs[0][0] + off);
        }
    }
    __syncthreads();

    #pragma unroll 2
    for (int ks = 0; ks < 24; ++ks) {
        const int cur = ks & 1;
        const int nxt = cur ^ 1;
        if (ks < 23) {
            const int kn = ks + 1;
            const float4 a = *(const float4*)(xsrc + kn * 32);
            const float4 b = *(const float4*)(xsrc + kn * 32 + 4);
            v8s v;
            v[0]=f2bf(a.x); v[1]=f2bf(a.y); v[2]=f2bf(a.z); v[3]=f2bf(a.w);
            v[4]=f2bf(b.x); v[5]=f2bf(b.y); v[6]=f2bf(b.z); v[7]=f2bf(b.w);
            *(v8s*)&As[nxt][sr * 32 + aslot * 8] = v;
            #pragma unroll
            for (int i = 0; i < 4; ++i) {
                const int crow = w * 64 + i * 16 + (l >> 2);
                const int off = __builtin_amdgcn_readfirstlane((w * 64 + i * 16) * 32);
                GLD16(hwe + (size_t)crow * ND + kn * 32 + (l & 3) * 8,
                      &Bs[nxt][0] + off);
            }
        }
        v8s af[4];
        #pragma unroll
        for (int mf = 0; mf < 4; ++mf) {
            const int row = mf * 16 + lm;
            af[mf] = *(const v8s*)&As[cur][row * 32 + (g ^ ((lm >> 1) & 3)) * 8];
        }
        #pragma unroll
        for (int nf = 0; nf < 4; ++nf) {
            const int cl = w * 64 + nf * 16 + lm;
            const v8s bv = *(const v8s*)&Bs[cur][cl * 32 + (g ^ ((cl >> 1) & 3)) * 8];
            #pragma unroll
            for (int mf = 0; mf < 4; ++mf)
                acc[mf][nf] = __builtin_amdgcn_mfma_f32_16x16x32_bf16(
                    af[mf], bv, acc[mf][nf], 0, 0, 0);
        }
        __syncthreads();
    }

    #pragma unroll
    for (int mf = 0; mf < 4; ++mf) {
        #pragma unroll
        for (int r = 0; r < 4; ++r) {
            const int rl = mf * 16 + g * 4 + r;
            const int orow = rows_s[rl];
            if (orow < 0) continue;
            const float rs = rs_s[rl], rm = rm_s[rl];
            float* op = out + (size_t)orow * NC;
            #pragma unroll
            for (int nf = 0; nf < 4; ++nf) {
                const int cl = w * 64 + nf * 16 + lm;
                const int c = n0 + cl;
                if (c < NC)
                    op[c] = acc[mf][nf][r] * rs - rm * css[cl] + hbs[cl];
            }
        }
    }
}

extern "C" void kernel_launch(void* const* d_in, const int* in_sizes, int n_in,
                              void* d_out, int out_size, void* d_ws, size_t ws_size,
                              hipStream_t stream) {
    const float* x     = (const float*)d_in[0];
    const float* gum   = (const float*)d_in[1];
    const float* w1    = (const float*)d_in[2];
    const float* b1    = (const float*)d_in[3];
    const float* w2    = (const float*)d_in[4];
    const float* b2    = (const float*)d_in[5];
    const float* gamma = (const float*)d_in[6];
    const float* beta  = (const float*)d_in[7];
    const float* hw    = (const float*)d_in[8];
    const float* hb    = (const float*)d_in[9];
    float* out = (float*)d_out;

    char* ws = (char*)d_ws;
    u64*    counts   = (u64*)ws;                    // packed 4x16-bit counters
    float2* murs     = (float2*)(ws + 256);         // 262144 B
    int*    rowlist  = (int*)(ws + 262400);         // 393216 B
    int*    redolist = (int*)(ws + 655616);         // 131072 B
    float*  hbias    = (float*)(ws + 786688);       // 6144 B
    float*  csumv    = (float*)(ws + 792832);       // 6144 B
    float*  bpartB   = (float*)(ws + 798976);       // 98304 B
    float*  bpartG   = (float*)(ws + 897280);       // 98304 B
    short*  w1bT     = (short*)(ws + 995584);       // 196608 B
    short*  hwbT     = (short*)(ws + 1192192);      // 2359296 B -> end 3551488

    hipMemsetAsync(counts, 0, 16, stream);
    prep_kernel<<<624, 256, 0, stream>>>(hw, gamma, w1, hwbT, w1bT);
    bias_part_kernel<<<dim3(3, 16), 256, 0, stream>>>(hw, beta, gamma, bpartB, bpartG);
    bias_comb_kernel<<<3, 256, 0, stream>>>(bpartB, bpartG, hb, hbias, csumv);
    selector_kernel<<<NB / 64, 256, 0, stream>>>(x, gum, w1bT, b1, w2, b2,
                                                 murs, counts, rowlist, redolist);
    redo_kernel<<<512, 128, 0, stream>>>(x, gum, w1, b1, w2, b2,
                                         counts, rowlist, redolist);
    head_kernel<<<dim3(2, NB / 64, NE), 256, 0, stream>>>(
        x, murs, hwbT, hbias, csumv, counts, rowlist, out);
}

// Round 9
// 206.132 us; speedup vs baseline: 1.5590x; 1.2095x over previous
//
#include <hip/hip_runtime.h>
#include <hip/hip_bf16.h>
#include <math.h>

#define NB 32768
#define ND 768
#define NC 474
#define NCP 512
#define NE 3
#define NH 128
#define GAP_THR 0.06f

typedef short v8s __attribute__((ext_vector_type(8)));
typedef float v4f __attribute__((ext_vector_type(4)));
typedef unsigned long long u64;

#define GLD16(gp, lp) __builtin_amdgcn_global_load_lds( \
    (const __attribute__((address_space(1))) void*)(gp), \
    (__attribute__((address_space(3))) void*)(lp), 16, 0, 0)

static __device__ __forceinline__ short f2bf(float f) {
    __hip_bfloat16 h = __float2bfloat16(f);
    return *reinterpret_cast<short*>(&h);
}

// ---------------------------------------------------------------------------
// prep: hwbT[e][c][k] = bf16(gamma[e][k]*hw[e][k][c]) transposed + slot-swizzled;
//       w1bT[c][k]    = bf16(w1[k][c]) same layout.
// Swizzle: within each 32-k (64B) group, 16B slot s -> s ^ ((c>>1)&3).
// ---------------------------------------------------------------------------
__global__ __launch_bounds__(256) void prep_kernel(
    const float* __restrict__ hw, const float* __restrict__ gamma,
    const float* __restrict__ w1,
    short* __restrict__ hwbT, short* __restrict__ w1bT)
{
    __shared__ float T[32][72];
    const int t = threadIdx.x;
    const int id = blockIdx.x;
    const float* src; short* dst; int stride, ncs; int e = 0, cc, kc;
    bool is_exp = (id < 576);
    if (is_exp) {
        e = id / 192; const int r2 = id % 192; cc = r2 / 24; kc = r2 % 24;
        src = hw + (size_t)e * ND * NC; stride = NC; ncs = NC;
        dst = hwbT + (size_t)e * NCP * ND;
    } else {
        const int j = id - 576; cc = j / 24; kc = j % 24;
        src = w1; stride = NH; ncs = NH; dst = w1bT;
    }
    const int c0 = cc * 64, k0 = kc * 32;
    {
        const int kl = t >> 3, c8 = (t & 7) * 8;
        const float g = is_exp ? gamma[e * ND + k0 + kl] : 1.f;
        #pragma unroll
        for (int j = 0; j < 8; ++j) {
            const int cg = c0 + c8 + j;
            const float v = (cg < ncs) ? src[(size_t)(k0 + kl) * stride + cg] : 0.f;
            T[kl][c8 + j] = v * g;
        }
    }
    __syncthreads();
    {
        const int cl = t >> 2, q = t & 3;
        const int cg = c0 + cl;
        const int sp = q ^ ((cg >> 1) & 3);
        union { short s[8]; int4 v; } u;
        #pragma unroll
        for (int j = 0; j < 8; ++j) u.s[j] = f2bf(T[q * 8 + j][cl]);
        *(int4*)(dst + (size_t)cg * ND + k0 + sp * 8) = u.v;
    }
}

// partials over 48-k chunks: bpB = beta@hw, bpG = gamma@hw
__global__ __launch_bounds__(256) void bias_part_kernel(
    const float* __restrict__ hw, const float* __restrict__ beta,
    const float* __restrict__ gamma,
    float* __restrict__ bpB, float* __restrict__ bpG)
{
    const int e = blockIdx.x, kc = blockIdx.y, t = threadIdx.x;
    const float* he = hw + (size_t)e * ND * NC;
    float a0 = 0.f, a1 = 0.f, g0 = 0.f, g1 = 0.f;
    const int c1 = t + 256;
    for (int k = kc * 48; k < kc * 48 + 48; ++k) {
        const float b = beta[e * ND + k];
        const float gm = gamma[e * ND + k];
        const float* row = he + (size_t)k * NC;
        const float v0 = row[t];
        a0 = fmaf(b, v0, a0);
        g0 = fmaf(gm, v0, g0);
        if (c1 < NC) {
            const float v1 = row[c1];
            a1 = fmaf(b, v1, a1);
            g1 = fmaf(gm, v1, g1);
        }
    }
    const size_t o = (size_t)(e * 16 + kc) * NCP;
    bpB[o + t] = a0;
    bpB[o + c1] = (c1 < NC) ? a1 : 0.f;
    bpG[o + t] = g0;
    bpG[o + c1] = (c1 < NC) ? g1 : 0.f;
}

__global__ __launch_bounds__(256) void bias_comb_kernel(
    const float* __restrict__ bpB, const float* __restrict__ bpG,
    const float* __restrict__ hb,
    float* __restrict__ hbias, float* __restrict__ csumv)
{
    const int e = blockIdx.x, t = threadIdx.x;
    #pragma unroll
    for (int h = 0; h < 2; ++h) {
        const int c = t + h * 256;
        float sb = 0.f, sg = 0.f;
        for (int kc = 0; kc < 16; ++kc) {
            sb += bpB[(size_t)(e * 16 + kc) * NCP + c];
            sg += bpG[(size_t)(e * 16 + kc) * NCP + c];
        }
        hbias[e * NCP + c] = (c < NC) ? hb[e * NC + c] + sb : 0.f;
        csumv[e * NCP + c] = (c < NC) ? sg : 0.f;
    }
}

// ---------------------------------------------------------------------------
// selector: 64 rows/block, burst A-stage + double-buffered B (GLD16).
// Epilogue: LN stats, logits, gap cascade; bucket append via ONE packed
// 64-bit atomic per block (4x16-bit fields), broadcast via __shfl (no LDS).
// ---------------------------------------------------------------------------
__global__ __launch_bounds__(256) void selector_kernel(
    const float* __restrict__ x, const float* __restrict__ gum,
    const short* __restrict__ w1bT, const float* __restrict__ b1,
    const float* __restrict__ w2, const float* __restrict__ b2,
    float2* __restrict__ murs, u64* __restrict__ counts,
    int* __restrict__ rowlist, int* __restrict__ redolist)
{
    __shared__ __align__(16) short As[64 * 392];   // 64 rows x 384k, stride 392
    __shared__ __align__(16) short Bs[2 * 4096];   // 2 x (128c x 32k)
    __shared__ float b1s[NH];
    __shared__ float w2s[NH * 3];
    __shared__ int besm[64];

    const int t = threadIdx.x;
    const int row0 = blockIdx.x * 64;
    const int w = t >> 6, l = t & 63;
    const int g = l >> 4, lm = l & 15;
    const int sr = t >> 2, sq = t & 3;

    if (t < NH) {
        b1s[t] = b1[t];
        w2s[t*3+0] = w2[t*3+0]; w2s[t*3+1] = w2[t*3+1]; w2s[t*3+2] = w2[t*3+2];
    }

    v4f acc[8];
    #pragma unroll
    for (int i = 0; i < 8; ++i) acc[i] = (v4f)(0.f);

    const float* xrow = x + (size_t)(row0 + sr) * ND + sq * 96;
    float s1 = 0.f, s2 = 0.f;
    int cur = 0;

    #pragma unroll 1
    for (int hf = 0; hf < 2; ++hf) {
        const int kh = hf * 384;
        float4 xv[24];
        #pragma unroll
        for (int i = 0; i < 24; ++i)
            xv[i] = *(const float4*)(xrow + kh + i * 4);
        #pragma unroll
        for (int i = 0; i < 2; ++i) {
            const int crow = w * 32 + i * 16 + (l >> 2);
            const int off = __builtin_amdgcn_readfirstlane(
                cur * 4096 + (w * 32 + i * 16) * 32);
            GLD16(w1bT + (size_t)crow * ND + kh + (l & 3) * 8, Bs + off);
        }
        __syncthreads();
        #pragma unroll
        for (int i = 0; i < 12; ++i) {
            const float4 a = xv[2*i], b = xv[2*i+1];
            s1 += a.x+a.y+a.z+a.w + b.x+b.y+b.z+b.w;
            s2 += a.x*a.x+a.y*a.y+a.z*a.z+a.w*a.w
                + b.x*b.x+b.y*b.y+b.z*b.z+b.w*b.w;
            v8s av;
            av[0]=f2bf(a.x); av[1]=f2bf(a.y); av[2]=f2bf(a.z); av[3]=f2bf(a.w);
            av[4]=f2bf(b.x); av[5]=f2bf(b.y); av[6]=f2bf(b.z); av[7]=f2bf(b.w);
            *(v8s*)&As[sr * 392 + sq * 96 + i * 8] = av;
        }
        __syncthreads();
        #pragma unroll 1
        for (int ks = 0; ks < 12; ++ks) {
            if (ks < 11) {
                #pragma unroll
                for (int i = 0; i < 2; ++i) {
                    const int crow = w * 32 + i * 16 + (l >> 2);
                    const int off = __builtin_amdgcn_readfirstlane(
                        (cur ^ 1) * 4096 + (w * 32 + i * 16) * 32);
                    GLD16(w1bT + (size_t)crow * ND + kh + (ks + 1) * 32 + (l & 3) * 8,
                          Bs + off);
                }
            }
            const v8s a = *(const v8s*)&As[(w * 16 + lm) * 392 + ks * 32 + g * 8];
            #pragma unroll
            for (int nf = 0; nf < 8; ++nf) {
                const int c = nf * 16 + lm;
                const v8s bv = *(const v8s*)&Bs[cur * 4096 + c * 32 + (g ^ ((c >> 1) & 3)) * 8];
                acc[nf] = __builtin_amdgcn_mfma_f32_16x16x32_bf16(a, bv, acc[nf], 0, 0, 0);
            }
            __syncthreads();
            cur ^= 1;
        }
    }

    // LN stats
    {
        float r1 = s1 + __shfl_xor(s1, 1);
        float r2 = s2 + __shfl_xor(s2, 1);
        r1 += __shfl_xor(r1, 2);
        r2 += __shfl_xor(r2, 2);
        if (sq == 0) {
            const float mu = r1 * (1.f/768.f);
            const float var = r2 * (1.f/768.f) - mu * mu;
            murs[row0 + sr] = make_float2(mu, rsqrtf(var + 1e-5f));
        }
    }

    // logits = relu(h + b1) @ w2, reduced across the 16 col-lanes
    float p[4][3];
    #pragma unroll
    for (int r = 0; r < 4; ++r) { p[r][0]=0.f; p[r][1]=0.f; p[r][2]=0.f; }
    #pragma unroll
    for (int nf = 0; nf < 8; ++nf) {
        const int c = nf * 16 + lm;
        const float bb = b1s[c];
        const float wa = w2s[c*3], wb = w2s[c*3+1], wcc = w2s[c*3+2];
        #pragma unroll
        for (int r = 0; r < 4; ++r) {
            const float h = fmaxf(acc[nf][r] + bb, 0.f);
            p[r][0] = fmaf(h, wa,  p[r][0]);
            p[r][1] = fmaf(h, wb,  p[r][1]);
            p[r][2] = fmaf(h, wcc, p[r][2]);
        }
    }
    #pragma unroll
    for (int m = 1; m < 16; m <<= 1) {
        #pragma unroll
        for (int r = 0; r < 4; ++r) {
            p[r][0] += __shfl_xor(p[r][0], m);
            p[r][1] += __shfl_xor(p[r][1], m);
            p[r][2] += __shfl_xor(p[r][2], m);
        }
    }
    if (lm == 0) {
        const float bb0 = b2[0], bb1 = b2[1], bb2 = b2[2];
        #pragma unroll
        for (int r = 0; r < 4; ++r) {
            const int rl = w * 16 + g * 4 + r;
            const int grow = row0 + rl;
            const float z0 = p[r][0] + bb0 + gum[grow*3+0];
            const float z1 = p[r][1] + bb1 + gum[grow*3+1];
            const float z2 = p[r][2] + bb2 + gum[grow*3+2];
            int be = 0; float best = z0;
            if (z1 > best) { best = z1; be = 1; }
            if (z2 > best) { best = z2; be = 2; }
            const float second = (be==0) ? fmaxf(z1,z2) : (be==1) ? fmaxf(z0,z2) : fmaxf(z0,z1);
            besm[rl] = (best - second < GAP_THR) ? 3 : be;
        }
    }
    __syncthreads();

    // wave 0: ballot-aggregate 64 decisions -> ONE packed atomic; shfl broadcast
    if (w == 0) {
        const int be = besm[l];
        const u64 m0 = __ballot(be == 0);
        const u64 m1 = __ballot(be == 1);
        const u64 m2 = __ballot(be == 2);
        const u64 m3 = __ballot(be == 3);
        u64 old = 0;
        if (l == 0) {
            const u64 add = (u64)__popcll(m0)
                          | ((u64)__popcll(m1) << 16)
                          | ((u64)__popcll(m2) << 32)
                          | ((u64)__popcll(m3) << 48);
            old = atomicAdd(counts, add);
        }
        const int blo = __shfl((int)(old & 0xFFFFFFFFull), 0);
        const int bhi = __shfl((int)(old >> 32), 0);
        old = ((u64)(unsigned)bhi << 32) | (u64)(unsigned)blo;
        const u64 mym = (be == 0) ? m0 : (be == 1) ? m1 : (be == 2) ? m2 : m3;
        const u64 below = (l == 63) ? 0x7FFFFFFFFFFFFFFFull : ((1ull << l) - 1ull);
        const int rank = __popcll(mym & below);
        const int base = (int)((old >> (16 * be)) & 0xFFFFull);
        const int idx = base + rank;
        const int grow = row0 + l;
        if (be < 3) {
            if ((unsigned)idx < NB) rowlist[be * NB + idx] = grow;
        } else {
            if ((unsigned)idx < NB) redolist[idx] = grow;
        }
    }
}

// fp64 redo for ambiguous rows: x-row staged in LDS, 8 independent fp64
// accumulator chains, 16 coalesced w1 loads in flight per unrolled iter.
__global__ __launch_bounds__(128) void redo_kernel(
    const float* __restrict__ x, const float* __restrict__ gum,
    const float* __restrict__ w1, const float* __restrict__ b1,
    const float* __restrict__ w2, const float* __restrict__ b2,
    u64* __restrict__ counts, int* __restrict__ rowlist,
    const int* __restrict__ redolist)
{
    const int t = threadIdx.x;
    int n = (int)((*counts >> 48) & 0xFFFFull);
    if (n > NB) n = NB;
    __shared__ float xs[ND];
    __shared__ double red[2][3];
    for (int i = blockIdx.x; i < n; i += gridDim.x) {
        const int row = redolist[i];
        // stage x row to LDS (192 float4s over 128 threads)
        {
            const float4* xp = (const float4*)(x + (size_t)row * ND);
            float4* xsv = (float4*)xs;
            xsv[t] = xp[t];
            if (t < 64) xsv[128 + t] = xp[128 + t];
        }
        __syncthreads();
        double h0 = 0.0, h1 = 0.0, h2 = 0.0, h3 = 0.0;
        double h4 = 0.0, h5 = 0.0, h6 = 0.0, h7 = 0.0;
        #pragma unroll 2
        for (int k = 0; k < ND; k += 8) {
            const float w0 = w1[(size_t)(k+0) * NH + t];
            const float w1v = w1[(size_t)(k+1) * NH + t];
            const float w2v = w1[(size_t)(k+2) * NH + t];
            const float w3 = w1[(size_t)(k+3) * NH + t];
            const float w4 = w1[(size_t)(k+4) * NH + t];
            const float w5 = w1[(size_t)(k+5) * NH + t];
            const float w6 = w1[(size_t)(k+6) * NH + t];
            const float w7 = w1[(size_t)(k+7) * NH + t];
            h0 = fma((double)xs[k+0], (double)w0, h0);
            h1 = fma((double)xs[k+1], (double)w1v, h1);
            h2 = fma((double)xs[k+2], (double)w2v, h2);
            h3 = fma((double)xs[k+3], (double)w3, h3);
            h4 = fma((double)xs[k+4], (double)w4, h4);
            h5 = fma((double)xs[k+5], (double)w5, h5);
            h6 = fma((double)xs[k+6], (double)w6, h6);
            h7 = fma((double)xs[k+7], (double)w7, h7);
        }
        double h = (((h0 + h1) + (h2 + h3)) + ((h4 + h5) + (h6 + h7)))
                 + (double)b1[t];
        h = h > 0.0 ? h : 0.0;
        double p0 = h * (double)w2[t * 3 + 0];
        double p1 = h * (double)w2[t * 3 + 1];
        double p2 = h * (double)w2[t * 3 + 2];
        #pragma unroll
        for (int m = 32; m >= 1; m >>= 1) {
            p0 += __shfl_xor(p0, m);
            p1 += __shfl_xor(p1, m);
            p2 += __shfl_xor(p2, m);
        }
        if ((t & 63) == 0) {
            red[t >> 6][0] = p0; red[t >> 6][1] = p1; red[t >> 6][2] = p2;
        }
        __syncthreads();
        if (t == 0) {
            double best = 0.0; int be = 0;
            #pragma unroll
            for (int e = 0; e < NE; ++e) {
                const double z = red[0][e] + red[1][e] + (double)b2[e]
                               + (double)gum[(size_t)row * 3 + e];
                if (e == 0 || z > best) { best = z; be = e; }
            }
            const u64 old = atomicAdd(counts, 1ull << (16 * be));
            const int pos = (int)((old >> (16 * be)) & 0xFFFFull);
            if ((unsigned)pos < NB) rowlist[be * NB + pos] = row;
        }
        __syncthreads();
    }
}

// ---------------------------------------------------------------------------
// head: grouped bf16 MFMA GEMM on RAW x (normalization folded into epilogue:
// out = rs*(x@Wg) - rs*mu*csum + hbias). BM=64 x BN=256, BK=32 double-buffered.
// A slab 4 KB from 32B/thread reg loads; B via GLD16. LDS ~43 KB -> 3 blk/CU.
// ---------------------------------------------------------------------------
__global__ __launch_bounds__(256, 3) void head_kernel(
    const float* __restrict__ x, const float2* __restrict__ murs,
    const short* __restrict__ hwbT, const float* __restrict__ hbias,
    const float* __restrict__ csumv,
    const u64* __restrict__ counts, const int* __restrict__ rowlist,
    float* __restrict__ out)
{
    const int e = blockIdx.z;
    int cnt = (int)((*counts >> (16 * e)) & 0xFFFFull);
    if (cnt > NB) cnt = NB;
    const int rc0 = blockIdx.y * 64;
    if (rc0 >= cnt) return;
    const int n0 = blockIdx.x * 256;

    __shared__ __align__(16) short As[2][64 * 32];   // dbuf 64 rows x 32k
    __shared__ __align__(16) short Bs[2][256 * 32];  // dbuf 256c x 32k
    __shared__ float hbs[256], css[256], rs_s[64], rm_s[64];
    __shared__ int rows_s[64];

    const int t = threadIdx.x;
    const int w = t >> 6, l = t & 63;
    const int g = l >> 4, lm = l & 15;
    const int sr = t >> 2, sq = t & 3;

    if (t < 64) {
        const int ri = rc0 + t;
        int rr = (ri < cnt) ? rowlist[e * NB + ri] : -1;
        if (rr >= NB) rr = -1;
        rows_s[t] = rr;
        const float2 mr = (rr >= 0) ? murs[rr] : make_float2(0.f, 0.f);
        rs_s[t] = mr.y;
        rm_s[t] = mr.y * mr.x;   // rs*mu
    }
    hbs[t] = (n0 + t < NC) ? hbias[e * NCP + n0 + t] : 0.f;
    css[t] = (n0 + t < NC) ? csumv[e * NCP + n0 + t] : 0.f;

    // this thread's A-source row (raw x, fp32)
    const int ridx = rc0 + sr;
    int arow = (ridx < cnt) ? rowlist[e * NB + ridx] : 0;
    if ((unsigned)arow >= NB) arow = 0;
    const float* xsrc = x + (size_t)arow * ND + sq * 8;
    const int aslot = sq ^ ((sr >> 1) & 3);       // write-side swizzle
    const short* hwe = hwbT + (size_t)e * NCP * ND + (size_t)n0 * ND;

    v4f acc[4][4];
    #pragma unroll
    for (int i = 0; i < 4; ++i)
        #pragma unroll
        for (int j = 0; j < 4; ++j) acc[i][j] = (v4f)(0.f);

    // prologue: stage ks=0
    {
        const float4 a = *(const float4*)(xsrc);
        const float4 b = *(const float4*)(xsrc + 4);
        v8s v;
        v[0]=f2bf(a.x); v[1]=f2bf(a.y); v[2]=f2bf(a.z); v[3]=f2bf(a.w);
        v[4]=f2bf(b.x); v[5]=f2bf(b.y); v[6]=f2bf(b.z); v[7]=f2bf(b.w);
        *(v8s*)&As[0][sr * 32 + aslot * 8] = v;
        #pragma unroll
        for (int i = 0; i < 4; ++i) {
            const int crow = w * 64 + i * 16 + (l >> 2);
            const int off = __builtin_amdgcn_readfirstlane((w * 64 + i * 16) * 32);
            GLD16(hwe + (size_t)crow * ND + (l & 3) * 8, &Bs[0][0] + off);
        }
    }
    __syncthreads();

    #pragma unroll 2
    for (int ks = 0; ks < 24; ++ks) {
        const int cur = ks & 1;
        const int nxt = cur ^ 1;
        if (ks < 23) {
            const int kn = ks + 1;
            const float4 a = *(const float4*)(xsrc + kn * 32);
            const float4 b = *(const float4*)(xsrc + kn * 32 + 4);
            v8s v;
            v[0]=f2bf(a.x); v[1]=f2bf(a.y); v[2]=f2bf(a.z); v[3]=f2bf(a.w);
            v[4]=f2bf(b.x); v[5]=f2bf(b.y); v[6]=f2bf(b.z); v[7]=f2bf(b.w);
            *(v8s*)&As[nxt][sr * 32 + aslot * 8] = v;
            #pragma unroll
            for (int i = 0; i < 4; ++i) {
                const int crow = w * 64 + i * 16 + (l >> 2);
                const int off = __builtin_amdgcn_readfirstlane((w * 64 + i * 16) * 32);
                GLD16(hwe + (size_t)crow * ND + kn * 32 + (l & 3) * 8,
                      &Bs[nxt][0] + off);
            }
        }
        v8s af[4];
        #pragma unroll
        for (int mf = 0; mf < 4; ++mf) {
            const int row = mf * 16 + lm;
            af[mf] = *(const v8s*)&As[cur][row * 32 + (g ^ ((lm >> 1) & 3)) * 8];
        }
        #pragma unroll
        for (int nf = 0; nf < 4; ++nf) {
            const int cl = w * 64 + nf * 16 + lm;
            const v8s bv = *(const v8s*)&Bs[cur][cl * 32 + (g ^ ((cl >> 1) & 3)) * 8];
            #pragma unroll
            for (int mf = 0; mf < 4; ++mf)
                acc[mf][nf] = __builtin_amdgcn_mfma_f32_16x16x32_bf16(
                    af[mf], bv, acc[mf][nf], 0, 0, 0);
        }
        __syncthreads();
    }

    #pragma unroll
    for (int mf = 0; mf < 4; ++mf) {
        #pragma unroll
        for (int r = 0; r < 4; ++r) {
            const int rl = mf * 16 + g * 4 + r;
            const int orow = rows_s[rl];
            if (orow < 0) continue;
            const float rs = rs_s[rl], rm = rm_s[rl];
            float* op = out + (size_t)orow * NC;
            #pragma unroll
            for (int nf = 0; nf < 4; ++nf) {
                const int cl = w * 64 + nf * 16 + lm;
                const int c = n0 + cl;
                if (c < NC)
                    op[c] = acc[mf][nf][r] * rs - rm * css[cl] + hbs[cl];
            }
        }
    }
}

extern "C" void kernel_launch(void* const* d_in, const int* in_sizes, int n_in,
                              void* d_out, int out_size, void* d_ws, size_t ws_size,
                              hipStream_t stream) {
    const float* x     = (const float*)d_in[0];
    const float* gum   = (const float*)d_in[1];
    const float* w1    = (const float*)d_in[2];
    const float* b1    = (const float*)d_in[3];
    const float* w2    = (const float*)d_in[4];
    const float* b2    = (const float*)d_in[5];
    const float* gamma = (const float*)d_in[6];
    const float* beta  = (const float*)d_in[7];
    const float* hw    = (const float*)d_in[8];
    const float* hb    = (const float*)d_in[9];
    float* out = (float*)d_out;

    char* ws = (char*)d_ws;
    u64*    counts   = (u64*)ws;                    // packed 4x16-bit counters
    float2* murs     = (float2*)(ws + 256);         // 262144 B
    int*    rowlist  = (int*)(ws + 262400);         // 393216 B
    int*    redolist = (int*)(ws + 655616);         // 131072 B
    float*  hbias    = (float*)(ws + 786688);       // 6144 B
    float*  csumv    = (float*)(ws + 792832);       // 6144 B
    float*  bpartB   = (float*)(ws + 798976);       // 98304 B
    float*  bpartG   = (float*)(ws + 897280);       // 98304 B
    short*  w1bT     = (short*)(ws + 995584);       // 196608 B
    short*  hwbT     = (short*)(ws + 1192192);      // 2359296 B -> end 3551488

    hipMemsetAsync(counts, 0, 16, stream);
    prep_kernel<<<624, 256, 0, stream>>>(hw, gamma, w1, hwbT, w1bT);
    bias_part_kernel<<<dim3(3, 16), 256, 0, stream>>>(hw, beta, gamma, bpartB, bpartG);
    bias_comb_kernel<<<3, 256, 0, stream>>>(bpartB, bpartG, hb, hbias, csumv);
    selector_kernel<<<NB / 64, 256, 0, stream>>>(x, gum, w1bT, b1, w2, b2,
                                                 murs, counts, rowlist, redolist);
    redo_kernel<<<512, 128, 0, stream>>>(x, gum, w1, b1, w2, b2,
                                         counts, rowlist, redolist);
    head_kernel<<<dim3(2, NB / 64, NE), 256, 0, stream>>>(
        x, murs, hwbT, hbias, csumv, counts, rowlist, out);
}

// Round 10
// 193.631 us; speedup vs baseline: 1.6596x; 1.0646x over previous
//
#include <hip/hip_runtime.h>
#include <hip/hip_bf16.h>
#include <math.h>

#define NB 32768
#define ND 768
#define NC 474
#define NCP 512
#define NE 3
#define NH 128
#define GAP_THR 0.06f
#define XB_OFF 4194304ull
#define WS_NEED (XB_OFF + (size_t)NB * ND * 2)

typedef short v8s __attribute__((ext_vector_type(8)));
typedef float v4f __attribute__((ext_vector_type(4)));
typedef unsigned long long u64;

#define GLD16(gp, lp) __builtin_amdgcn_global_load_lds( \
    (const __attribute__((address_space(1))) void*)(gp), \
    (__attribute__((address_space(3))) void*)(lp), 16, 0, 0)

static __device__ __forceinline__ short f2bf(float f) {
    __hip_bfloat16 h = __float2bfloat16(f);
    return *reinterpret_cast<short*>(&h);
}

// ---------------------------------------------------------------------------
// prep: hwbT[e][c][k] = bf16(gamma[e][k]*hw[e][k][c]) transposed + slot-swizzled;
//       w1bT[c][k]    = bf16(w1[k][c]) same layout.
// Swizzle: within each 32-k (64B) group, 16B slot s -> s ^ ((c>>1)&3).
// ---------------------------------------------------------------------------
__global__ __launch_bounds__(256) void prep_kernel(
    const float* __restrict__ hw, const float* __restrict__ gamma,
    const float* __restrict__ w1,
    short* __restrict__ hwbT, short* __restrict__ w1bT)
{
    __shared__ float T[32][72];
    const int t = threadIdx.x;
    const int id = blockIdx.x;
    const float* src; short* dst; int stride, ncs; int e = 0, cc, kc;
    bool is_exp = (id < 576);
    if (is_exp) {
        e = id / 192; const int r2 = id % 192; cc = r2 / 24; kc = r2 % 24;
        src = hw + (size_t)e * ND * NC; stride = NC; ncs = NC;
        dst = hwbT + (size_t)e * NCP * ND;
    } else {
        const int j = id - 576; cc = j / 24; kc = j % 24;
        src = w1; stride = NH; ncs = NH; dst = w1bT;
    }
    const int c0 = cc * 64, k0 = kc * 32;
    {
        const int kl = t >> 3, c8 = (t & 7) * 8;
        const float g = is_exp ? gamma[e * ND + k0 + kl] : 1.f;
        #pragma unroll
        for (int j = 0; j < 8; ++j) {
            const int cg = c0 + c8 + j;
            const float v = (cg < ncs) ? src[(size_t)(k0 + kl) * stride + cg] : 0.f;
            T[kl][c8 + j] = v * g;
        }
    }
    __syncthreads();
    {
        const int cl = t >> 2, q = t & 3;
        const int cg = c0 + cl;
        const int sp = q ^ ((cg >> 1) & 3);
        union { short s[8]; int4 v; } u;
        #pragma unroll
        for (int j = 0; j < 8; ++j) u.s[j] = f2bf(T[q * 8 + j][cl]);
        *(int4*)(dst + (size_t)cg * ND + k0 + sp * 8) = u.v;
    }
}

// partials over 48-k chunks: bpB = beta@hw, bpG = gamma@hw
__global__ __launch_bounds__(256) void bias_part_kernel(
    const float* __restrict__ hw, const float* __restrict__ beta,
    const float* __restrict__ gamma,
    float* __restrict__ bpB, float* __restrict__ bpG)
{
    const int e = blockIdx.x, kc = blockIdx.y, t = threadIdx.x;
    const float* he = hw + (size_t)e * ND * NC;
    float a0 = 0.f, a1 = 0.f, g0 = 0.f, g1 = 0.f;
    const int c1 = t + 256;
    for (int k = kc * 48; k < kc * 48 + 48; ++k) {
        const float b = beta[e * ND + k];
        const float gm = gamma[e * ND + k];
        const float* row = he + (size_t)k * NC;
        const float v0 = row[t];
        a0 = fmaf(b, v0, a0);
        g0 = fmaf(gm, v0, g0);
        if (c1 < NC) {
            const float v1 = row[c1];
            a1 = fmaf(b, v1, a1);
            g1 = fmaf(gm, v1, g1);
        }
    }
    const size_t o = (size_t)(e * 16 + kc) * NCP;
    bpB[o + t] = a0;
    bpB[o + c1] = (c1 < NC) ? a1 : 0.f;
    bpG[o + t] = g0;
    bpG[o + c1] = (c1 < NC) ? g1 : 0.f;
}

__global__ __launch_bounds__(256) void bias_comb_kernel(
    const float* __restrict__ bpB, const float* __restrict__ bpG,
    const float* __restrict__ hb,
    float* __restrict__ hbias, float* __restrict__ csumv)
{
    const int e = blockIdx.x, t = threadIdx.x;
    #pragma unroll
    for (int h = 0; h < 2; ++h) {
        const int c = t + h * 256;
        float sb = 0.f, sg = 0.f;
        for (int kc = 0; kc < 16; ++kc) {
            sb += bpB[(size_t)(e * 16 + kc) * NCP + c];
            sg += bpG[(size_t)(e * 16 + kc) * NCP + c];
        }
        hbias[e * NCP + c] = (c < NC) ? hb[e * NC + c] + sb : 0.f;
        csumv[e * NCP + c] = (c < NC) ? sg : 0.f;
    }
}

// ---------------------------------------------------------------------------
// selector: 64 rows/block, burst A-stage + double-buffered B (GLD16).
// Also stores bf16(raw x) to xbg (if non-null) for the head's A-path.
// Epilogue: LN stats, logits, gap cascade, packed-atomic bucket append.
// ---------------------------------------------------------------------------
__global__ __launch_bounds__(256) void selector_kernel(
    const float* __restrict__ x, const float* __restrict__ gum,
    const short* __restrict__ w1bT, const float* __restrict__ b1,
    const float* __restrict__ w2, const float* __restrict__ b2,
    float2* __restrict__ murs, u64* __restrict__ counts,
    int* __restrict__ rowlist, int* __restrict__ redolist,
    short* __restrict__ xbg)
{
    __shared__ __align__(16) short As[64 * 392];   // 64 rows x 384k, stride 392
    __shared__ __align__(16) short Bs[2 * 4096];   // 2 x (128c x 32k)
    __shared__ float b1s[NH];
    __shared__ float w2s[NH * 3];
    __shared__ int besm[64];

    const int t = threadIdx.x;
    const int row0 = blockIdx.x * 64;
    const int w = t >> 6, l = t & 63;
    const int g = l >> 4, lm = l & 15;
    const int sr = t >> 2, sq = t & 3;

    if (t < NH) {
        b1s[t] = b1[t];
        w2s[t*3+0] = w2[t*3+0]; w2s[t*3+1] = w2[t*3+1]; w2s[t*3+2] = w2[t*3+2];
    }

    v4f acc[8];
    #pragma unroll
    for (int i = 0; i < 8; ++i) acc[i] = (v4f)(0.f);

    const float* xrow = x + (size_t)(row0 + sr) * ND + sq * 96;
    short* xbrow = xbg ? (xbg + (size_t)(row0 + sr) * ND + sq * 96) : (short*)0;
    float s1 = 0.f, s2 = 0.f;
    int cur = 0;

    #pragma unroll 1
    for (int hf = 0; hf < 2; ++hf) {
        const int kh = hf * 384;
        float4 xv[24];
        #pragma unroll
        for (int i = 0; i < 24; ++i)
            xv[i] = *(const float4*)(xrow + kh + i * 4);
        #pragma unroll
        for (int i = 0; i < 2; ++i) {
            const int crow = w * 32 + i * 16 + (l >> 2);
            const int off = __builtin_amdgcn_readfirstlane(
                cur * 4096 + (w * 32 + i * 16) * 32);
            GLD16(w1bT + (size_t)crow * ND + kh + (l & 3) * 8, Bs + off);
        }
        __syncthreads();
        #pragma unroll
        for (int i = 0; i < 12; ++i) {
            const float4 a = xv[2*i], b = xv[2*i+1];
            s1 += a.x+a.y+a.z+a.w + b.x+b.y+b.z+b.w;
            s2 += a.x*a.x+a.y*a.y+a.z*a.z+a.w*a.w
                + b.x*b.x+b.y*b.y+b.z*b.z+b.w*b.w;
            v8s av;
            av[0]=f2bf(a.x); av[1]=f2bf(a.y); av[2]=f2bf(a.z); av[3]=f2bf(a.w);
            av[4]=f2bf(b.x); av[5]=f2bf(b.y); av[6]=f2bf(b.z); av[7]=f2bf(b.w);
            *(v8s*)&As[sr * 392 + sq * 96 + i * 8] = av;
            if (xbg) *(v8s*)(xbrow + kh + i * 8) = av;
        }
        __syncthreads();
        #pragma unroll 1
        for (int ks = 0; ks < 12; ++ks) {
            if (ks < 11) {
                #pragma unroll
                for (int i = 0; i < 2; ++i) {
                    const int crow = w * 32 + i * 16 + (l >> 2);
                    const int off = __builtin_amdgcn_readfirstlane(
                        (cur ^ 1) * 4096 + (w * 32 + i * 16) * 32);
                    GLD16(w1bT + (size_t)crow * ND + kh + (ks + 1) * 32 + (l & 3) * 8,
                          Bs + off);
                }
            }
            const v8s a = *(const v8s*)&As[(w * 16 + lm) * 392 + ks * 32 + g * 8];
            #pragma unroll
            for (int nf = 0; nf < 8; ++nf) {
                const int c = nf * 16 + lm;
                const v8s bv = *(const v8s*)&Bs[cur * 4096 + c * 32 + (g ^ ((c >> 1) & 3)) * 8];
                acc[nf] = __builtin_amdgcn_mfma_f32_16x16x32_bf16(a, bv, acc[nf], 0, 0, 0);
            }
            __syncthreads();
            cur ^= 1;
        }
    }

    // LN stats
    {
        float r1 = s1 + __shfl_xor(s1, 1);
        float r2 = s2 + __shfl_xor(s2, 1);
        r1 += __shfl_xor(r1, 2);
        r2 += __shfl_xor(r2, 2);
        if (sq == 0) {
            const float mu = r1 * (1.f/768.f);
            const float var = r2 * (1.f/768.f) - mu * mu;
            murs[row0 + sr] = make_float2(mu, rsqrtf(var + 1e-5f));
        }
    }

    // logits = relu(h + b1) @ w2, reduced across the 16 col-lanes
    float p[4][3];
    #pragma unroll
    for (int r = 0; r < 4; ++r) { p[r][0]=0.f; p[r][1]=0.f; p[r][2]=0.f; }
    #pragma unroll
    for (int nf = 0; nf < 8; ++nf) {
        const int c = nf * 16 + lm;
        const float bb = b1s[c];
        const float wa = w2s[c*3], wb = w2s[c*3+1], wcc = w2s[c*3+2];
        #pragma unroll
        for (int r = 0; r < 4; ++r) {
            const float h = fmaxf(acc[nf][r] + bb, 0.f);
            p[r][0] = fmaf(h, wa,  p[r][0]);
            p[r][1] = fmaf(h, wb,  p[r][1]);
            p[r][2] = fmaf(h, wcc, p[r][2]);
        }
    }
    #pragma unroll
    for (int m = 1; m < 16; m <<= 1) {
        #pragma unroll
        for (int r = 0; r < 4; ++r) {
            p[r][0] += __shfl_xor(p[r][0], m);
            p[r][1] += __shfl_xor(p[r][1], m);
            p[r][2] += __shfl_xor(p[r][2], m);
        }
    }
    if (lm == 0) {
        const float bb0 = b2[0], bb1 = b2[1], bb2 = b2[2];
        #pragma unroll
        for (int r = 0; r < 4; ++r) {
            const int rl = w * 16 + g * 4 + r;
            const int grow = row0 + rl;
            const float z0 = p[r][0] + bb0 + gum[grow*3+0];
            const float z1 = p[r][1] + bb1 + gum[grow*3+1];
            const float z2 = p[r][2] + bb2 + gum[grow*3+2];
            int be = 0; float best = z0;
            if (z1 > best) { best = z1; be = 1; }
            if (z2 > best) { best = z2; be = 2; }
            const float second = (be==0) ? fmaxf(z1,z2) : (be==1) ? fmaxf(z0,z2) : fmaxf(z0,z1);
            besm[rl] = (best - second < GAP_THR) ? 3 : be;
        }
    }
    __syncthreads();

    // wave 0: ballot-aggregate 64 decisions -> ONE packed atomic; shfl broadcast
    if (w == 0) {
        const int be = besm[l];
        const u64 m0 = __ballot(be == 0);
        const u64 m1 = __ballot(be == 1);
        const u64 m2 = __ballot(be == 2);
        const u64 m3 = __ballot(be == 3);
        u64 old = 0;
        if (l == 0) {
            const u64 add = (u64)__popcll(m0)
                          | ((u64)__popcll(m1) << 16)
                          | ((u64)__popcll(m2) << 32)
                          | ((u64)__popcll(m3) << 48);
            old = atomicAdd(counts, add);
        }
        const int blo = __shfl((int)(old & 0xFFFFFFFFull), 0);
        const int bhi = __shfl((int)(old >> 32), 0);
        old = ((u64)(unsigned)bhi << 32) | (u64)(unsigned)blo;
        const u64 mym = (be == 0) ? m0 : (be == 1) ? m1 : (be == 2) ? m2 : m3;
        const u64 below = (l == 63) ? 0x7FFFFFFFFFFFFFFFull : ((1ull << l) - 1ull);
        const int rank = __popcll(mym & below);
        const int base = (int)((old >> (16 * be)) & 0xFFFFull);
        const int idx = base + rank;
        const int grow = row0 + l;
        if (be < 3) {
            if ((unsigned)idx < NB) rowlist[be * NB + idx] = grow;
        } else {
            if ((unsigned)idx < NB) redolist[idx] = grow;
        }
    }
}

// fp64 redo for ambiguous rows: x-row staged in LDS, 8 independent fp64
// accumulator chains, 16 coalesced w1 loads in flight per unrolled iter.
__global__ __launch_bounds__(128) void redo_kernel(
    const float* __restrict__ x, const float* __restrict__ gum,
    const float* __restrict__ w1, const float* __restrict__ b1,
    const float* __restrict__ w2, const float* __restrict__ b2,
    u64* __restrict__ counts, int* __restrict__ rowlist,
    const int* __restrict__ redolist)
{
    const int t = threadIdx.x;
    int n = (int)((*counts >> 48) & 0xFFFFull);
    if (n > NB) n = NB;
    __shared__ float xs[ND];
    __shared__ double red[2][3];
    for (int i = blockIdx.x; i < n; i += gridDim.x) {
        const int row = redolist[i];
        {
            const float4* xp = (const float4*)(x + (size_t)row * ND);
            float4* xsv = (float4*)xs;
            xsv[t] = xp[t];
            if (t < 64) xsv[128 + t] = xp[128 + t];
        }
        __syncthreads();
        double h0 = 0.0, h1 = 0.0, h2 = 0.0, h3 = 0.0;
        double h4 = 0.0, h5 = 0.0, h6 = 0.0, h7 = 0.0;
        #pragma unroll 2
        for (int k = 0; k < ND; k += 8) {
            const float w0 = w1[(size_t)(k+0) * NH + t];
            const float w1v = w1[(size_t)(k+1) * NH + t];
            const float w2v = w1[(size_t)(k+2) * NH + t];
            const float w3 = w1[(size_t)(k+3) * NH + t];
            const float w4 = w1[(size_t)(k+4) * NH + t];
            const float w5 = w1[(size_t)(k+5) * NH + t];
            const float w6 = w1[(size_t)(k+6) * NH + t];
            const float w7 = w1[(size_t)(k+7) * NH + t];
            h0 = fma((double)xs[k+0], (double)w0, h0);
            h1 = fma((double)xs[k+1], (double)w1v, h1);
            h2 = fma((double)xs[k+2], (double)w2v, h2);
            h3 = fma((double)xs[k+3], (double)w3, h3);
            h4 = fma((double)xs[k+4], (double)w4, h4);
            h5 = fma((double)xs[k+5], (double)w5, h5);
            h6 = fma((double)xs[k+6], (double)w6, h6);
            h7 = fma((double)xs[k+7], (double)w7, h7);
        }
        double h = (((h0 + h1) + (h2 + h3)) + ((h4 + h5) + (h6 + h7)))
                 + (double)b1[t];
        h = h > 0.0 ? h : 0.0;
        double p0 = h * (double)w2[t * 3 + 0];
        double p1 = h * (double)w2[t * 3 + 1];
        double p2 = h * (double)w2[t * 3 + 2];
        #pragma unroll
        for (int m = 32; m >= 1; m >>= 1) {
            p0 += __shfl_xor(p0, m);
            p1 += __shfl_xor(p1, m);
            p2 += __shfl_xor(p2, m);
        }
        if ((t & 63) == 0) {
            red[t >> 6][0] = p0; red[t >> 6][1] = p1; red[t >> 6][2] = p2;
        }
        __syncthreads();
        if (t == 0) {
            double best = 0.0; int be = 0;
            #pragma unroll
            for (int e = 0; e < NE; ++e) {
                const double z = red[0][e] + red[1][e] + (double)b2[e]
                               + (double)gum[(size_t)row * 3 + e];
                if (e == 0 || z > best) { best = z; be = e; }
            }
            const u64 old = atomicAdd(counts, 1ull << (16 * be));
            const int pos = (int)((old >> (16 * be)) & 0xFFFFull);
            if ((unsigned)pos < NB) rowlist[be * NB + pos] = row;
        }
        __syncthreads();
    }
}

// ---------------------------------------------------------------------------
// head: grouped bf16 MFMA GEMM on raw x (norm folded into epilogue).
// XB=1: A staged via GLD16 from precomputed bf16 xb (pre-swizzled source).
// XB=0: A staged from fp32 x with cvt (fallback when ws too small).
// BM=64 x BN=256, BK=32 double-buffered, ~43 KB LDS -> 3 blk/CU.
// ---------------------------------------------------------------------------
template<int XB>
__global__ __launch_bounds__(256, 3) void head_kernel(
    const float* __restrict__ x, const short* __restrict__ xb,
    const float2* __restrict__ murs,
    const short* __restrict__ hwbT, const float* __restrict__ hbias,
    const float* __restrict__ csumv,
    const u64* __restrict__ counts, const int* __restrict__ rowlist,
    float* __restrict__ out)
{
    const int e = blockIdx.z;
    int cnt = (int)((*counts >> (16 * e)) & 0xFFFFull);
    if (cnt > NB) cnt = NB;
    const int rc0 = blockIdx.y * 64;
    if (rc0 >= cnt) return;
    const int n0 = blockIdx.x * 256;

    __shared__ __align__(16) short As[2][64 * 32];   // dbuf 64 rows x 32k
    __shared__ __align__(16) short Bs[2][256 * 32];  // dbuf 256c x 32k
    __shared__ float hbs[256], css[256], rs_s[64], rm_s[64];
    __shared__ int rows_s[64];

    const int t = threadIdx.x;
    const int w = t >> 6, l = t & 63;
    const int g = l >> 4, lm = l & 15;
    const int sr = t >> 2, sq = t & 3;       // sr == w*16 + (l>>2); sq == (l&3)

    if (t < 64) {
        const int ri = rc0 + t;
        int rr = (ri < cnt) ? rowlist[e * NB + ri] : -1;
        if (rr >= NB) rr = -1;
        rows_s[t] = rr;
        const float2 mr = (rr >= 0) ? murs[rr] : make_float2(0.f, 0.f);
        rs_s[t] = mr.y;
        rm_s[t] = mr.y * mr.x;   // rs*mu
    }
    hbs[t] = (n0 + t < NC) ? hbias[e * NCP + n0 + t] : 0.f;
    css[t] = (n0 + t < NC) ? csumv[e * NCP + n0 + t] : 0.f;

    const int ridx = rc0 + sr;
    int arow = (ridx < cnt) ? rowlist[e * NB + ridx] : 0;
    if ((unsigned)arow >= NB) arow = 0;
    const int aslot = sq ^ ((sr >> 1) & 3);       // swizzled slot
    const float* xsrc = x + (size_t)arow * ND + sq * 8;        // XB=0 path
    const short* axsrc = xb ? (xb + (size_t)arow * ND + aslot * 8) : (short*)0; // XB=1
    const short* hwe = hwbT + (size_t)e * NCP * ND + (size_t)n0 * ND;

    v4f acc[4][4];
    #pragma unroll
    for (int i = 0; i < 4; ++i)
        #pragma unroll
        for (int j = 0; j < 4; ++j) acc[i][j] = (v4f)(0.f);

    // prologue: stage ks=0
    if (XB) {
        const int aoff = __builtin_amdgcn_readfirstlane(w * 512);
        GLD16(axsrc, &As[0][0] + aoff);
    } else {
        const float4 a = *(const float4*)(xsrc);
        const float4 b = *(const float4*)(xsrc + 4);
        v8s v;
        v[0]=f2bf(a.x); v[1]=f2bf(a.y); v[2]=f2bf(a.z); v[3]=f2bf(a.w);
        v[4]=f2bf(b.x); v[5]=f2bf(b.y); v[6]=f2bf(b.z); v[7]=f2bf(b.w);
        *(v8s*)&As[0][sr * 32 + aslot * 8] = v;
    }
    #pragma unroll
    for (int i = 0; i < 4; ++i) {
        const int crow = w * 64 + i * 16 + (l >> 2);
        const int off = __builtin_amdgcn_readfirstlane((w * 64 + i * 16) * 32);
        GLD16(hwe + (size_t)crow * ND + (l & 3) * 8, &Bs[0][0] + off);
    }
    __syncthreads();

    #pragma unroll 2
    for (int ks = 0; ks < 24; ++ks) {
        const int cur = ks & 1;
        const int nxt = cur ^ 1;
        if (ks < 23) {
            const int kn = ks + 1;
            if (XB) {
                const int aoff = __builtin_amdgcn_readfirstlane(nxt * 2048 + w * 512);
                GLD16(axsrc + kn * 32, &As[0][0] + aoff);
            } else {
                const float4 a = *(const float4*)(xsrc + kn * 32);
                const float4 b = *(const float4*)(xsrc + kn * 32 + 4);
                v8s v;
                v[0]=f2bf(a.x); v[1]=f2bf(a.y); v[2]=f2bf(a.z); v[3]=f2bf(a.w);
                v[4]=f2bf(b.x); v[5]=f2bf(b.y); v[6]=f2bf(b.z); v[7]=f2bf(b.w);
                *(v8s*)&As[nxt][sr * 32 + aslot * 8] = v;
            }
            #pragma unroll
            for (int i = 0; i < 4; ++i) {
                const int crow = w * 64 + i * 16 + (l >> 2);
                const int off = __builtin_amdgcn_readfirstlane((w * 64 + i * 16) * 32);
                GLD16(hwe + (size_t)crow * ND + kn * 32 + (l & 3) * 8,
                      &Bs[nxt][0] + off);
            }
        }
        v8s af[4];
        #pragma unroll
        for (int mf = 0; mf < 4; ++mf) {
            const int row = mf * 16 + lm;
            af[mf] = *(const v8s*)&As[cur][row * 32 + (g ^ ((lm >> 1) & 3)) * 8];
        }
        #pragma unroll
        for (int nf = 0; nf < 4; ++nf) {
            const int cl = w * 64 + nf * 16 + lm;
            const v8s bv = *(const v8s*)&Bs[cur][cl * 32 + (g ^ ((cl >> 1) & 3)) * 8];
            #pragma unroll
            for (int mf = 0; mf < 4; ++mf)
                acc[mf][nf] = __builtin_amdgcn_mfma_f32_16x16x32_bf16(
                    af[mf], bv, acc[mf][nf], 0, 0, 0);
        }
        __syncthreads();
    }

    #pragma unroll
    for (int mf = 0; mf < 4; ++mf) {
        #pragma unroll
        for (int r = 0; r < 4; ++r) {
            const int rl = mf * 16 + g * 4 + r;
            const int orow = rows_s[rl];
            if (orow < 0) continue;
            const float rs = rs_s[rl], rm = rm_s[rl];
            float* op = out + (size_t)orow * NC;
            #pragma unroll
            for (int nf = 0; nf < 4; ++nf) {
                const int cl = w * 64 + nf * 16 + lm;
                const int c = n0 + cl;
                if (c < NC)
                    op[c] = acc[mf][nf][r] * rs - rm * css[cl] + hbs[cl];
            }
        }
    }
}

extern "C" void kernel_launch(void* const* d_in, const int* in_sizes, int n_in,
                              void* d_out, int out_size, void* d_ws, size_t ws_size,
                              hipStream_t stream) {
    const float* x     = (const float*)d_in[0];
    const float* gum   = (const float*)d_in[1];
    const float* w1    = (const float*)d_in[2];
    const float* b1    = (const float*)d_in[3];
    const float* w2    = (const float*)d_in[4];
    const float* b2    = (const float*)d_in[5];
    const float* gamma = (const float*)d_in[6];
    const float* beta  = (const float*)d_in[7];
    const float* hw    = (const float*)d_in[8];
    const float* hb    = (const float*)d_in[9];
    float* out = (float*)d_out;

    char* ws = (char*)d_ws;
    u64*    counts   = (u64*)ws;                    // packed 4x16-bit counters
    float2* murs     = (float2*)(ws + 256);         // 262144 B
    int*    rowlist  = (int*)(ws + 262400);         // 393216 B
    int*    redolist = (int*)(ws + 655616);         // 131072 B
    float*  hbias    = (float*)(ws + 786688);       // 6144 B
    float*  csumv    = (float*)(ws + 792832);       // 6144 B
    float*  bpartB   = (float*)(ws + 798976);       // 98304 B
    float*  bpartG   = (float*)(ws + 897280);       // 98304 B
    short*  w1bT     = (short*)(ws + 995584);       // 196608 B
    short*  hwbT     = (short*)(ws + 1192192);      // 2359296 B -> end 3551488
    const bool use_xb = ws_size >= WS_NEED;
    short*  xbg      = use_xb ? (short*)(ws + XB_OFF) : (short*)0; // 50 MB

    hipMemsetAsync(counts, 0, 16, stream);
    prep_kernel<<<624, 256, 0, stream>>>(hw, gamma, w1, hwbT, w1bT);
    bias_part_kernel<<<dim3(3, 16), 256, 0, stream>>>(hw, beta, gamma, bpartB, bpartG);
    bias_comb_kernel<<<3, 256, 0, stream>>>(bpartB, bpartG, hb, hbias, csumv);
    selector_kernel<<<NB / 64, 256, 0, stream>>>(x, gum, w1bT, b1, w2, b2,
                                                 murs, counts, rowlist, redolist, xbg);
    redo_kernel<<<512, 128, 0, stream>>>(x, gum, w1, b1, w2, b2,
                                         counts, rowlist, redolist);
    if (use_xb)
        head_kernel<1><<<dim3(2, NB / 64, NE), 256, 0, stream>>>(
            x, xbg, murs, hwbT, hbias, csumv, counts, rowlist, out);
    else
        head_kernel<0><<<dim3(2, NB / 64, NE), 256, 0, stream>>>(
            x, (const short*)0, murs, hwbT, hbias, csumv, counts, rowlist, out);
}

// Round 11
// 193.469 us; speedup vs baseline: 1.6610x; 1.0008x over previous
//
#include <hip/hip_runtime.h>
#include <hip/hip_bf16.h>
#include <math.h>

#define NB 32768
#define ND 768
#define NC 474
#define NCP 512
#define NE 3
#define NH 128
#define GAP_THR 0.06f
#define XB_OFF 4194304ull
#define WS_NEED (XB_OFF + (size_t)NB * ND * 2)

typedef short v8s __attribute__((ext_vector_type(8)));
typedef float v4f __attribute__((ext_vector_type(4)));
typedef unsigned long long u64;

#define GLD16(gp, lp) __builtin_amdgcn_global_load_lds( \
    (const __attribute__((address_space(1))) void*)(gp), \
    (__attribute__((address_space(3))) void*)(lp), 16, 0, 0)

static __device__ __forceinline__ short f2bf(float f) {
    __hip_bfloat16 h = __float2bfloat16(f);
    return *reinterpret_cast<short*>(&h);
}

// ---------------------------------------------------------------------------
// prep: hwbT[e][c][k] = bf16(gamma[e][k]*hw[e][k][c]) transposed + slot-swizzled;
//       w1bT[c][k]    = bf16(w1[k][c]) same layout.
// Swizzle: within each 32-k (64B) group, 16B slot s -> s ^ ((c>>1)&3).
// ---------------------------------------------------------------------------
__global__ __launch_bounds__(256) void prep_kernel(
    const float* __restrict__ hw, const float* __restrict__ gamma,
    const float* __restrict__ w1,
    short* __restrict__ hwbT, short* __restrict__ w1bT)
{
    __shared__ float T[32][72];
    const int t = threadIdx.x;
    const int id = blockIdx.x;
    const float* src; short* dst; int stride, ncs; int e = 0, cc, kc;
    bool is_exp = (id < 576);
    if (is_exp) {
        e = id / 192; const int r2 = id % 192; cc = r2 / 24; kc = r2 % 24;
        src = hw + (size_t)e * ND * NC; stride = NC; ncs = NC;
        dst = hwbT + (size_t)e * NCP * ND;
    } else {
        const int j = id - 576; cc = j / 24; kc = j % 24;
        src = w1; stride = NH; ncs = NH; dst = w1bT;
    }
    const int c0 = cc * 64, k0 = kc * 32;
    {
        const int kl = t >> 3, c8 = (t & 7) * 8;
        const float g = is_exp ? gamma[e * ND + k0 + kl] : 1.f;
        #pragma unroll
        for (int j = 0; j < 8; ++j) {
            const int cg = c0 + c8 + j;
            const float v = (cg < ncs) ? src[(size_t)(k0 + kl) * stride + cg] : 0.f;
            T[kl][c8 + j] = v * g;
        }
    }
    __syncthreads();
    {
        const int cl = t >> 2, q = t & 3;
        const int cg = c0 + cl;
        const int sp = q ^ ((cg >> 1) & 3);
        union { short s[8]; int4 v; } u;
        #pragma unroll
        for (int j = 0; j < 8; ++j) u.s[j] = f2bf(T[q * 8 + j][cl]);
        *(int4*)(dst + (size_t)cg * ND + k0 + sp * 8) = u.v;
    }
}

// partials over 48-k chunks: bpB = beta@hw, bpG = gamma@hw
__global__ __launch_bounds__(256) void bias_part_kernel(
    const float* __restrict__ hw, const float* __restrict__ beta,
    const float* __restrict__ gamma,
    float* __restrict__ bpB, float* __restrict__ bpG)
{
    const int e = blockIdx.x, kc = blockIdx.y, t = threadIdx.x;
    const float* he = hw + (size_t)e * ND * NC;
    float a0 = 0.f, a1 = 0.f, g0 = 0.f, g1 = 0.f;
    const int c1 = t + 256;
    for (int k = kc * 48; k < kc * 48 + 48; ++k) {
        const float b = beta[e * ND + k];
        const float gm = gamma[e * ND + k];
        const float* row = he + (size_t)k * NC;
        const float v0 = row[t];
        a0 = fmaf(b, v0, a0);
        g0 = fmaf(gm, v0, g0);
        if (c1 < NC) {
            const float v1 = row[c1];
            a1 = fmaf(b, v1, a1);
            g1 = fmaf(gm, v1, g1);
        }
    }
    const size_t o = (size_t)(e * 16 + kc) * NCP;
    bpB[o + t] = a0;
    bpB[o + c1] = (c1 < NC) ? a1 : 0.f;
    bpG[o + t] = g0;
    bpG[o + c1] = (c1 < NC) ? g1 : 0.f;
}

__global__ __launch_bounds__(256) void bias_comb_kernel(
    const float* __restrict__ bpB, const float* __restrict__ bpG,
    const float* __restrict__ hb,
    float* __restrict__ hbias, float* __restrict__ csumv)
{
    const int e = blockIdx.x, t = threadIdx.x;
    #pragma unroll
    for (int h = 0; h < 2; ++h) {
        const int c = t + h * 256;
        float sb = 0.f, sg = 0.f;
        for (int kc = 0; kc < 16; ++kc) {
            sb += bpB[(size_t)(e * 16 + kc) * NCP + c];
            sg += bpG[(size_t)(e * 16 + kc) * NCP + c];
        }
        hbias[e * NCP + c] = (c < NC) ? hb[e * NC + c] + sb : 0.f;
        csumv[e * NCP + c] = (c < NC) ? sg : 0.f;
    }
}

// ---------------------------------------------------------------------------
// selector: 64 rows/block, burst A-stage + double-buffered B (GLD16).
// Also stores bf16(raw x) to xbg (if non-null) for the head's A-path.
// Epilogue: LN stats, logits, gap cascade, packed-atomic bucket append.
// ---------------------------------------------------------------------------
__global__ __launch_bounds__(256) void selector_kernel(
    const float* __restrict__ x, const float* __restrict__ gum,
    const short* __restrict__ w1bT, const float* __restrict__ b1,
    const float* __restrict__ w2, const float* __restrict__ b2,
    float2* __restrict__ murs, u64* __restrict__ counts,
    int* __restrict__ rowlist, int* __restrict__ redolist,
    short* __restrict__ xbg)
{
    __shared__ __align__(16) short As[64 * 392];   // 64 rows x 384k, stride 392
    __shared__ __align__(16) short Bs[2 * 4096];   // 2 x (128c x 32k)
    __shared__ float b1s[NH];
    __shared__ float w2s[NH * 3];
    __shared__ int besm[64];

    const int t = threadIdx.x;
    const int row0 = blockIdx.x * 64;
    const int w = t >> 6, l = t & 63;
    const int g = l >> 4, lm = l & 15;
    const int sr = t >> 2, sq = t & 3;

    if (t < NH) {
        b1s[t] = b1[t];
        w2s[t*3+0] = w2[t*3+0]; w2s[t*3+1] = w2[t*3+1]; w2s[t*3+2] = w2[t*3+2];
    }

    v4f acc[8];
    #pragma unroll
    for (int i = 0; i < 8; ++i) acc[i] = (v4f)(0.f);

    const float* xrow = x + (size_t)(row0 + sr) * ND + sq * 96;
    short* xbrow = xbg ? (xbg + (size_t)(row0 + sr) * ND + sq * 96) : (short*)0;
    float s1 = 0.f, s2 = 0.f;
    int cur = 0;

    #pragma unroll 1
    for (int hf = 0; hf < 2; ++hf) {
        const int kh = hf * 384;
        float4 xv[24];
        #pragma unroll
        for (int i = 0; i < 24; ++i)
            xv[i] = *(const float4*)(xrow + kh + i * 4);
        #pragma unroll
        for (int i = 0; i < 2; ++i) {
            const int crow = w * 32 + i * 16 + (l >> 2);
            const int off = __builtin_amdgcn_readfirstlane(
                cur * 4096 + (w * 32 + i * 16) * 32);
            GLD16(w1bT + (size_t)crow * ND + kh + (l & 3) * 8, Bs + off);
        }
        __syncthreads();
        #pragma unroll
        for (int i = 0; i < 12; ++i) {
            const float4 a = xv[2*i], b = xv[2*i+1];
            s1 += a.x+a.y+a.z+a.w + b.x+b.y+b.z+b.w;
            s2 += a.x*a.x+a.y*a.y+a.z*a.z+a.w*a.w
                + b.x*b.x+b.y*b.y+b.z*b.z+b.w*b.w;
            v8s av;
            av[0]=f2bf(a.x); av[1]=f2bf(a.y); av[2]=f2bf(a.z); av[3]=f2bf(a.w);
            av[4]=f2bf(b.x); av[5]=f2bf(b.y); av[6]=f2bf(b.z); av[7]=f2bf(b.w);
            *(v8s*)&As[sr * 392 + sq * 96 + i * 8] = av;
            if (xbg) *(v8s*)(xbrow + kh + i * 8) = av;
        }
        __syncthreads();
        #pragma unroll 1
        for (int ks = 0; ks < 12; ++ks) {
            if (ks < 11) {
                #pragma unroll
                for (int i = 0; i < 2; ++i) {
                    const int crow = w * 32 + i * 16 + (l >> 2);
                    const int off = __builtin_amdgcn_readfirstlane(
                        (cur ^ 1) * 4096 + (w * 32 + i * 16) * 32);
                    GLD16(w1bT + (size_t)crow * ND + kh + (ks + 1) * 32 + (l & 3) * 8,
                          Bs + off);
                }
            }
            const v8s a = *(const v8s*)&As[(w * 16 + lm) * 392 + ks * 32 + g * 8];
            #pragma unroll
            for (int nf = 0; nf < 8; ++nf) {
                const int c = nf * 16 + lm;
                const v8s bv = *(const v8s*)&Bs[cur * 4096 + c * 32 + (g ^ ((c >> 1) & 3)) * 8];
                acc[nf] = __builtin_amdgcn_mfma_f32_16x16x32_bf16(a, bv, acc[nf], 0, 0, 0);
            }
            __syncthreads();
            cur ^= 1;
        }
    }

    // LN stats
    {
        float r1 = s1 + __shfl_xor(s1, 1);
        float r2 = s2 + __shfl_xor(s2, 1);
        r1 += __shfl_xor(r1, 2);
        r2 += __shfl_xor(r2, 2);
        if (sq == 0) {
            const float mu = r1 * (1.f/768.f);
            const float var = r2 * (1.f/768.f) - mu * mu;
            murs[row0 + sr] = make_float2(mu, rsqrtf(var + 1e-5f));
        }
    }

    // logits = relu(h + b1) @ w2, reduced across the 16 col-lanes
    float p[4][3];
    #pragma unroll
    for (int r = 0; r < 4; ++r) { p[r][0]=0.f; p[r][1]=0.f; p[r][2]=0.f; }
    #pragma unroll
    for (int nf = 0; nf < 8; ++nf) {
        const int c = nf * 16 + lm;
        const float bb = b1s[c];
        const float wa = w2s[c*3], wb = w2s[c*3+1], wcc = w2s[c*3+2];
        #pragma unroll
        for (int r = 0; r < 4; ++r) {
            const float h = fmaxf(acc[nf][r] + bb, 0.f);
            p[r][0] = fmaf(h, wa,  p[r][0]);
            p[r][1] = fmaf(h, wb,  p[r][1]);
            p[r][2] = fmaf(h, wcc, p[r][2]);
        }
    }
    #pragma unroll
    for (int m = 1; m < 16; m <<= 1) {
        #pragma unroll
        for (int r = 0; r < 4; ++r) {
            p[r][0] += __shfl_xor(p[r][0], m);
            p[r][1] += __shfl_xor(p[r][1], m);
            p[r][2] += __shfl_xor(p[r][2], m);
        }
    }
    if (lm == 0) {
        const float bb0 = b2[0], bb1 = b2[1], bb2 = b2[2];
        #pragma unroll
        for (int r = 0; r < 4; ++r) {
            const int rl = w * 16 + g * 4 + r;
            const int grow = row0 + rl;
            const float z0 = p[r][0] + bb0 + gum[grow*3+0];
            const float z1 = p[r][1] + bb1 + gum[grow*3+1];
            const float z2 = p[r][2] + bb2 + gum[grow*3+2];
            int be = 0; float best = z0;
            if (z1 > best) { best = z1; be = 1; }
            if (z2 > best) { best = z2; be = 2; }
            const float second = (be==0) ? fmaxf(z1,z2) : (be==1) ? fmaxf(z0,z2) : fmaxf(z0,z1);
            besm[rl] = (best - second < GAP_THR) ? 3 : be;
        }
    }
    __syncthreads();

    // wave 0: ballot-aggregate 64 decisions -> ONE packed atomic; shfl broadcast
    if (w == 0) {
        const int be = besm[l];
        const u64 m0 = __ballot(be == 0);
        const u64 m1 = __ballot(be == 1);
        const u64 m2 = __ballot(be == 2);
        const u64 m3 = __ballot(be == 3);
        u64 old = 0;
        if (l == 0) {
            const u64 add = (u64)__popcll(m0)
                          | ((u64)__popcll(m1) << 16)
                          | ((u64)__popcll(m2) << 32)
                          | ((u64)__popcll(m3) << 48);
            old = atomicAdd(counts, add);
        }
        const int blo = __shfl((int)(old & 0xFFFFFFFFull), 0);
        const int bhi = __shfl((int)(old >> 32), 0);
        old = ((u64)(unsigned)bhi << 32) | (u64)(unsigned)blo;
        const u64 mym = (be == 0) ? m0 : (be == 1) ? m1 : (be == 2) ? m2 : m3;
        const u64 below = (l == 63) ? 0x7FFFFFFFFFFFFFFFull : ((1ull << l) - 1ull);
        const int rank = __popcll(mym & below);
        const int base = (int)((old >> (16 * be)) & 0xFFFFull);
        const int idx = base + rank;
        const int grow = row0 + l;
        if (be < 3) {
            if ((unsigned)idx < NB) rowlist[be * NB + idx] = grow;
        } else {
            if ((unsigned)idx < NB) redolist[idx] = grow;
        }
    }
}

// fp64 redo for ambiguous rows: x-row staged in LDS, 8 independent fp64
// accumulator chains, 16 coalesced w1 loads in flight per unrolled iter.
__global__ __launch_bounds__(128) void redo_kernel(
    const float* __restrict__ x, const float* __restrict__ gum,
    const float* __restrict__ w1, const float* __restrict__ b1,
    const float* __restrict__ w2, const float* __restrict__ b2,
    u64* __restrict__ counts, int* __restrict__ rowlist,
    const int* __restrict__ redolist)
{
    const int t = threadIdx.x;
    int n = (int)((*counts >> 48) & 0xFFFFull);
    if (n > NB) n = NB;
    __shared__ float xs[ND];
    __shared__ double red[2][3];
    for (int i = blockIdx.x; i < n; i += gridDim.x) {
        const int row = redolist[i];
        {
            const float4* xp = (const float4*)(x + (size_t)row * ND);
            float4* xsv = (float4*)xs;
            xsv[t] = xp[t];
            if (t < 64) xsv[128 + t] = xp[128 + t];
        }
        __syncthreads();
        double h0 = 0.0, h1 = 0.0, h2 = 0.0, h3 = 0.0;
        double h4 = 0.0, h5 = 0.0, h6 = 0.0, h7 = 0.0;
        #pragma unroll 2
        for (int k = 0; k < ND; k += 8) {
            const float w0 = w1[(size_t)(k+0) * NH + t];
            const float w1v = w1[(size_t)(k+1) * NH + t];
            const float w2v = w1[(size_t)(k+2) * NH + t];
            const float w3 = w1[(size_t)(k+3) * NH + t];
            const float w4 = w1[(size_t)(k+4) * NH + t];
            const float w5 = w1[(size_t)(k+5) * NH + t];
            const float w6 = w1[(size_t)(k+6) * NH + t];
            const float w7 = w1[(size_t)(k+7) * NH + t];
            h0 = fma((double)xs[k+0], (double)w0, h0);
            h1 = fma((double)xs[k+1], (double)w1v, h1);
            h2 = fma((double)xs[k+2], (double)w2v, h2);
            h3 = fma((double)xs[k+3], (double)w3, h3);
            h4 = fma((double)xs[k+4], (double)w4, h4);
            h5 = fma((double)xs[k+5], (double)w5, h5);
            h6 = fma((double)xs[k+6], (double)w6, h6);
            h7 = fma((double)xs[k+7], (double)w7, h7);
        }
        double h = (((h0 + h1) + (h2 + h3)) + ((h4 + h5) + (h6 + h7)))
                 + (double)b1[t];
        h = h > 0.0 ? h : 0.0;
        double p0 = h * (double)w2[t * 3 + 0];
        double p1 = h * (double)w2[t * 3 + 1];
        double p2 = h * (double)w2[t * 3 + 2];
        #pragma unroll
        for (int m = 32; m >= 1; m >>= 1) {
            p0 += __shfl_xor(p0, m);
            p1 += __shfl_xor(p1, m);
            p2 += __shfl_xor(p2, m);
        }
        if ((t & 63) == 0) {
            red[t >> 6][0] = p0; red[t >> 6][1] = p1; red[t >> 6][2] = p2;
        }
        __syncthreads();
        if (t == 0) {
            double best = 0.0; int be = 0;
            #pragma unroll
            for (int e = 0; e < NE; ++e) {
                const double z = red[0][e] + red[1][e] + (double)b2[e]
                               + (double)gum[(size_t)row * 3 + e];
                if (e == 0 || z > best) { best = z; be = e; }
            }
            const u64 old = atomicAdd(counts, 1ull << (16 * be));
            const int pos = (int)((old >> (16 * be)) & 0xFFFFull);
            if ((unsigned)pos < NB) rowlist[be * NB + pos] = row;
        }
        __syncthreads();
    }
}

// ---------------------------------------------------------------------------
// head: grouped bf16 MFMA GEMM on raw x (norm folded into epilogue).
// XB=1: A staged via GLD16 from precomputed bf16 xb (pre-swizzled source).
// Counted-vmcnt pipeline (T4): per step {issue 5 GLD16 -> vmcnt(5) ->
// barrier -> 16 MFMA -> barrier}; loads stay in flight across barriers.
// ---------------------------------------------------------------------------
template<int XB>
__global__ __launch_bounds__(256, 3) void head_kernel(
    const float* __restrict__ x, const short* __restrict__ xb,
    const float2* __restrict__ murs,
    const short* __restrict__ hwbT, const float* __restrict__ hbias,
    const float* __restrict__ csumv,
    const u64* __restrict__ counts, const int* __restrict__ rowlist,
    float* __restrict__ out)
{
    const int e = blockIdx.z;
    int cnt = (int)((*counts >> (16 * e)) & 0xFFFFull);
    if (cnt > NB) cnt = NB;
    const int rc0 = blockIdx.y * 64;
    if (rc0 >= cnt) return;
    const int n0 = blockIdx.x * 256;

    __shared__ __align__(16) short As[2][64 * 32];   // dbuf 64 rows x 32k
    __shared__ __align__(16) short Bs[2][256 * 32];  // dbuf 256c x 32k
    __shared__ float hbs[256], css[256], rs_s[64], rm_s[64];
    __shared__ int rows_s[64];

    const int t = threadIdx.x;
    const int w = t >> 6, l = t & 63;
    const int g = l >> 4, lm = l & 15;
    const int sr = t >> 2, sq = t & 3;       // sr == w*16 + (l>>2); sq == (l&3)

    if (t < 64) {
        const int ri = rc0 + t;
        int rr = (ri < cnt) ? rowlist[e * NB + ri] : -1;
        if (rr >= NB) rr = -1;
        rows_s[t] = rr;
        const float2 mr = (rr >= 0) ? murs[rr] : make_float2(0.f, 0.f);
        rs_s[t] = mr.y;
        rm_s[t] = mr.y * mr.x;   // rs*mu
    }
    hbs[t] = (n0 + t < NC) ? hbias[e * NCP + n0 + t] : 0.f;
    css[t] = (n0 + t < NC) ? csumv[e * NCP + n0 + t] : 0.f;

    const int ridx = rc0 + sr;
    int arow = (ridx < cnt) ? rowlist[e * NB + ridx] : 0;
    if ((unsigned)arow >= NB) arow = 0;
    const int aslot = sq ^ ((sr >> 1) & 3);       // swizzled slot
    const float* xsrc = x + (size_t)arow * ND + sq * 8;        // XB=0 path
    const short* axsrc = xb ? (xb + (size_t)arow * ND + aslot * 8) : (short*)0; // XB=1
    const short* hwe = hwbT + (size_t)e * NCP * ND + (size_t)n0 * ND;

    v4f acc[4][4];
    #pragma unroll
    for (int i = 0; i < 4; ++i)
        #pragma unroll
        for (int j = 0; j < 4; ++j) acc[i][j] = (v4f)(0.f);

    // prologue: issue stage for ks=0 (no wait yet)
    if (XB) {
        const int aoff = __builtin_amdgcn_readfirstlane(w * 512);
        GLD16(axsrc, &As[0][0] + aoff);
    } else {
        const float4 a = *(const float4*)(xsrc);
        const float4 b = *(const float4*)(xsrc + 4);
        v8s v;
        v[0]=f2bf(a.x); v[1]=f2bf(a.y); v[2]=f2bf(a.z); v[3]=f2bf(a.w);
        v[4]=f2bf(b.x); v[5]=f2bf(b.y); v[6]=f2bf(b.z); v[7]=f2bf(b.w);
        *(v8s*)&As[0][sr * 32 + aslot * 8] = v;
    }
    #pragma unroll
    for (int i = 0; i < 4; ++i) {
        const int crow = w * 64 + i * 16 + (l >> 2);
        const int off = __builtin_amdgcn_readfirstlane((w * 64 + i * 16) * 32);
        GLD16(hwe + (size_t)crow * ND + (l & 3) * 8, &Bs[0][0] + off);
    }

    #pragma unroll 2
    for (int ks = 0; ks < 24; ++ks) {
        const int cur = ks & 1;
        const int nxt = cur ^ 1;
        if (ks < 23) {
            const int kn = ks + 1;
            if (XB) {
                const int aoff = __builtin_amdgcn_readfirstlane(nxt * 2048 + w * 512);
                GLD16(axsrc + kn * 32, &As[0][0] + aoff);
            } else {
                const float4 a = *(const float4*)(xsrc + kn * 32);
                const float4 b = *(const float4*)(xsrc + kn * 32 + 4);
                v8s v;
                v[0]=f2bf(a.x); v[1]=f2bf(a.y); v[2]=f2bf(a.z); v[3]=f2bf(a.w);
                v[4]=f2bf(b.x); v[5]=f2bf(b.y); v[6]=f2bf(b.z); v[7]=f2bf(b.w);
                *(v8s*)&As[nxt][sr * 32 + aslot * 8] = v;
            }
            #pragma unroll
            for (int i = 0; i < 4; ++i) {
                const int crow = w * 64 + i * 16 + (l >> 2);
                const int off = __builtin_amdgcn_readfirstlane((w * 64 + i * 16) * 32);
                GLD16(hwe + (size_t)crow * ND + kn * 32 + (l & 3) * 8,
                      &Bs[nxt][0] + off);
            }
            // wait only the PREVIOUS step's loads (5 just issued stay in flight)
            if (XB) asm volatile("s_waitcnt vmcnt(5)" ::: "memory");
            else    asm volatile("s_waitcnt vmcnt(4)" ::: "memory");
        } else {
            asm volatile("s_waitcnt vmcnt(0)" ::: "memory");
        }
        __builtin_amdgcn_sched_barrier(0);
        __builtin_amdgcn_s_barrier();   // all waves: cur fully landed

        v8s af[4];
        #pragma unroll
        for (int mf = 0; mf < 4; ++mf) {
            const int row = mf * 16 + lm;
            af[mf] = *(const v8s*)&As[cur][row * 32 + (g ^ ((lm >> 1) & 3)) * 8];
        }
        #pragma unroll
        for (int nf = 0; nf < 4; ++nf) {
            const int cl = w * 64 + nf * 16 + lm;
            const v8s bv = *(const v8s*)&Bs[cur][cl * 32 + (g ^ ((cl >> 1) & 3)) * 8];
            #pragma unroll
            for (int mf = 0; mf < 4; ++mf)
                acc[mf][nf] = __builtin_amdgcn_mfma_f32_16x16x32_bf16(
                    af[mf], bv, acc[mf][nf], 0, 0, 0);
        }
        asm volatile("s_waitcnt lgkmcnt(0)" ::: "memory");
        __builtin_amdgcn_sched_barrier(0);
        __builtin_amdgcn_s_barrier();   // reads of cur done before overwrite
    }

    #pragma unroll
    for (int mf = 0; mf < 4; ++mf) {
        #pragma unroll
        for (int r = 0; r < 4; ++r) {
            const int rl = mf * 16 + g * 4 + r;
            const int orow = rows_s[rl];
            if (orow < 0) continue;
            const float rs = rs_s[rl], rm = rm_s[rl];
            float* op = out + (size_t)orow * NC;
            #pragma unroll
            for (int nf = 0; nf < 4; ++nf) {
                const int cl = w * 64 + nf * 16 + lm;
                const int c = n0 + cl;
                if (c < NC)
                    op[c] = acc[mf][nf][r] * rs - rm * css[cl] + hbs[cl];
            }
        }
    }
}

extern "C" void kernel_launch(void* const* d_in, const int* in_sizes, int n_in,
                              void* d_out, int out_size, void* d_ws, size_t ws_size,
                              hipStream_t stream) {
    const float* x     = (const float*)d_in[0];
    const float* gum   = (const float*)d_in[1];
    const float* w1    = (const float*)d_in[2];
    const float* b1    = (const float*)d_in[3];
    const float* w2    = (const float*)d_in[4];
    const float* b2    = (const float*)d_in[5];
    const float* gamma = (const float*)d_in[6];
    const float* beta  = (const float*)d_in[7];
    const float* hw    = (const float*)d_in[8];
    const float* hb    = (const float*)d_in[9];
    float* out = (float*)d_out;

    char* ws = (char*)d_ws;
    u64*    counts   = (u64*)ws;                    // packed 4x16-bit counters
    float2* murs     = (float2*)(ws + 256);         // 262144 B
    int*    rowlist  = (int*)(ws + 262400);         // 393216 B
    int*    redolist = (int*)(ws + 655616);         // 131072 B
    float*  hbias    = (float*)(ws + 786688);       // 6144 B
    float*  csumv    = (float*)(ws + 792832);       // 6144 B
    float*  bpartB   = (float*)(ws + 798976);       // 98304 B
    float*  bpartG   = (float*)(ws + 897280);       // 98304 B
    short*  w1bT     = (short*)(ws + 995584);       // 196608 B
    short*  hwbT     = (short*)(ws + 1192192);      // 2359296 B -> end 3551488
    const bool use_xb = ws_size >= WS_NEED;
    short*  xbg      = use_xb ? (short*)(ws + XB_OFF) : (short*)0; // 50 MB

    hipMemsetAsync(counts, 0, 16, stream);
    prep_kernel<<<624, 256, 0, stream>>>(hw, gamma, w1, hwbT, w1bT);
    bias_part_kernel<<<dim3(3, 16), 256, 0, stream>>>(hw, beta, gamma, bpartB, bpartG);
    bias_comb_kernel<<<3, 256, 0, stream>>>(bpartB, bpartG, hb, hbias, csumv);
    selector_kernel<<<NB / 64, 256, 0, stream>>>(x, gum, w1bT, b1, w2, b2,
                                                 murs, counts, rowlist, redolist, xbg);
    redo_kernel<<<512, 128, 0, stream>>>(x, gum, w1, b1, w2, b2,
                                         counts, rowlist, redolist);
    if (use_xb)
        head_kernel<1><<<dim3(2, NB / 64, NE), 256, 0, stream>>>(
            x, xbg, murs, hwbT, hbias, csumv, counts, rowlist, out);
    else
        head_kernel<0><<<dim3(2, NB / 64, NE), 256, 0, stream>>>(
            x, (const short*)0, murs, hwbT, hbias, csumv, counts, rowlist, out);
}